// Round 5
// baseline (343.433 us; speedup 1.0000x reference)
//
#include <hip/hip_runtime.h>

#define N_PTS 20000
#define CIN   32
#define COUT  64
#define KK    4
#define KF    64
#define KDIM  2048          // KF*CIN
#define E_PAD 262144
#define EPS   1e-12f
#define FOUR_OVER_PI 1.27323954473516f
#define QB    8             // queries per block (fallback kernel)
#define MT16  16            // queries per block (fused kernel)

typedef __attribute__((ext_vector_type(8))) short bf16x8;
typedef __attribute__((ext_vector_type(4))) float f32x4;

__device__ __forceinline__ float sgnf(float v) {
    return v > 0.f ? 1.f : (v < 0.f ? -1.f : 0.f);
}
__device__ __forceinline__ int imin(int a, int b) { return a < b ? a : b; }
__device__ __forceinline__ int imax(int a, int b) { return a > b ? a : b; }

__device__ __forceinline__ unsigned short f2bf(float f) {   // RNE f32->bf16
    unsigned u = __float_as_uint(f);
    u = u + 0x7fffu + ((u >> 16) & 1u);
    return (unsigned short)(u >> 16);
}

// ball_to_cube_volume_preserving + trilinear cell (f32, op-for-op vs ref).
__device__ __forceinline__ void edge_geom(
    const float* __restrict__ pos, int n, int q,
    int& cellb, float& ofx, float& ofy, float& ofz)
{
    const float rx = (pos[n * 3 + 0] - pos[q * 3 + 0]) * 20.f;
    const float ry = (pos[n * 3 + 1] - pos[q * 3 + 1]) * 20.f;
    const float rz = (pos[n * 3 + 2] - pos[q * 3 + 2]) * 20.f;
    const float sq   = rx * rx + ry * ry + rz * rz;
    const float nrm  = sqrtf(fmaxf(sq, EPS));
    const float rxy2 = rx * rx + ry * ry;
    const bool  top  = (1.25f * rz * rz > rxy2);
    const float s_top  = sqrtf(fmaxf(3.f * nrm / (nrm + fabsf(rz) + EPS), EPS));
    const float s_side = nrm / sqrtf(fmaxf(rxy2, EPS));
    float cx = top ? rx * s_top : rx * s_side;
    float cy = top ? ry * s_top : ry * s_side;
    float cz = top ? sgnf(rz) * nrm : 1.5f * rz;
    if (sq < EPS) { cx = 0.f; cy = 0.f; cz = 0.f; }
    const float rc2 = cx * cx + cy * cy;
    const float rxy = sqrtf(fmaxf(rc2, EPS));
    const bool  xbig = fabsf(cy) <= fabsf(cx);
    const float safe_x = (fabsf(cx) > EPS) ? cx : 1.f;
    const float safe_y = (fabsf(cy) > EPS) ? cy : 1.f;
    const float qxv = sgnf(cx) * rxy;
    const float qyv = sgnf(cy) * rxy;
    float bx = xbig ? qxv : qyv * FOUR_OVER_PI * atanf(cx / safe_y);
    float by = xbig ? qxv * FOUR_OVER_PI * atanf(cy / safe_x) : qyv;
    if (rc2 < EPS) { bx = 0.f; by = 0.f; }
    const float ux = fminf(fmaxf((bx + 1.f) * 0.5f * 3.f, 0.f), 3.f);
    const float uy = fminf(fmaxf((by + 1.f) * 0.5f * 3.f, 0.f), 3.f);
    const float uz = fminf(fmaxf((cz + 1.f) * 0.5f * 3.f, 0.f), 3.f);
    const int ix = imin(imax((int)floorf(ux), 0), 2);
    const int iy = imin(imax((int)floorf(uy), 0), 2);
    const int iz = imin(imax((int)floorf(uz), 0), 2);
    cellb = (iz * KK + iy) * KK + ix;
    ofx = ux - (float)ix; ofy = uy - (float)iy; ofz = uz - (float)iz;
}

// CSR offsets from sorted edge_q (padding keyed to N_PTS).
__global__ __launch_bounds__(256) void build_qstart_kernel(
    const int* __restrict__ eq, const float* __restrict__ ev,
    int stride, int* __restrict__ qstart)
{
    int e = blockIdx.x * 256 + threadIdx.x;
    if (e >= E_PAD) return;
    int k = (ev[e] > 0.f) ? eq[e * stride] : N_PTS;
    if (k > N_PTS) k = N_PTS;
    int kp = -1;
    if (e > 0) {
        kp = (ev[e - 1] > 0.f) ? eq[(e - 1) * stride] : N_PTS;
        if (kp > N_PTS) kp = N_PTS;
    }
    for (int q = kp + 1; q <= k; ++q) qstart[q] = e;
    if (e == E_PAD - 1) {
        for (int q = k + 1; q <= N_PTS; ++q) qstart[q] = E_PAD;
    }
}

// Per-edge geometry -> records. rec_m.y packs cell | (q << 6).
__global__ __launch_bounds__(256) void geom_kernel(
    const float* __restrict__ pos,
    const int* __restrict__ eq, const int* __restrict__ en,
    int strideQ, int strideN,
    int2* __restrict__ rec_m, float4* __restrict__ rec_f)
{
    const int e = blockIdx.x * 256 + threadIdx.x;
    if (e >= E_PAD) return;
    const int q = eq[e * strideQ];
    const int n = en[e * strideN];
    int ib; float fx, fy, fz;
    edge_geom(pos, n, q, ib, fx, fy, fz);
    rec_m[e] = make_int2(n, ib | (q << 6));
    rec_f[e] = make_float4(fx, fy, fz, 0.f);
}

// W[2048][64] f32 -> bf16 in B-fragment order: Wfrag[ks][nf][lane][j].
__global__ __launch_bounds__(256) void reorder_w_kernel(
    const float* __restrict__ Wconv, unsigned short* __restrict__ Wfrag)
{
    const int idx = blockIdx.x * 256 + threadIdx.x;   // 131072 total
    const int j    = idx & 7;
    const int lane = (idx >> 3) & 63;
    const int nf   = (idx >> 9) & 3;
    const int ks   = idx >> 11;
    const int k    = ks * 32 + ((lane >> 4) << 3) + j;
    const int col  = nf * 16 + (lane & 15);
    Wfrag[idx] = f2bf(Wconv[k * COUT + col]);
}

// Fused scatter + GEMM. 16 queries/block, Z f32 in LDS (swizzled),
// edge-parallel phase A with ds_add_f32, MFMA phase B from LDS.
__global__ __launch_bounds__(512, 1) void fused_kernel(
    const float* __restrict__ feats,
    const unsigned short* __restrict__ Wfrag,
    const float* __restrict__ Wd, const float* __restrict__ bd,
    const int2* __restrict__ rec_m, const float4* __restrict__ rec_f,
    const int* __restrict__ qstart, float* __restrict__ out)
{
    __shared__ float4 Zf4[MT16 * KDIM / 4];     // 128 KB, 16B aligned
    __shared__ float  partial[2][MT16][COUT];   // 8 KB
    float* Zf = (float*)Zf4;

    const int t    = threadIdx.x;
    const int w    = t >> 6;
    const int lane = t & 63;
    const int q0   = blockIdx.x * MT16;

    // zero Z (swizzle is a within-row permutation; zero everything)
    {
        const float4 z4 = {0.f, 0.f, 0.f, 0.f};
        #pragma unroll
        for (int i = 0; i < MT16 * KDIM / 4 / 512; ++i)
            Zf4[i * 512 + t] = z4;
    }
    const int e0 = qstart[q0];
    const int e1 = qstart[q0 + MT16];
    __syncthreads();

    // ---------- Phase A: edge-parallel scatter with LDS f32 atomics ----
    // lane = (ci, dbase). Wave-uniform edge index (stride 8 across waves).
    {
        const int ci    = lane & 31;
        const int dbase = lane >> 5;
        int e = e0 + w;
        int2 mA = {0, 0}, mB = {0, 0};
        float4 fA = {0, 0, 0, 0}, fB = {0, 0, 0, 0};
        float ftA = 0.f;
        if (e < e1)     { mA = rec_m[e];     fA = rec_f[e];
                          ftA = feats[(size_t)mA.x * CIN + ci]; }
        if (e + 8 < e1) { mB = rec_m[e + 8]; fB = rec_f[e + 8]; }
        while (e < e1) {
            int2 mC = {0, 0}; float4 fC = {0, 0, 0, 0}; float ftB = 0.f;
            if (e + 16 < e1) { mC = rec_m[e + 16]; fC = rec_f[e + 16]; }
            if (e + 8  < e1) { ftB = feats[(size_t)mB.x * CIN + ci]; }

            const int ib  = mA.y & 63;
            const int row = (mA.y >> 6) - q0;
            const int rsw = row & 7;
            const int rbase = row * KDIM;
            const float wxf = dbase ? fA.x : 1.f - fA.x;
            const float wy0 = 1.f - fA.y, wy1 = fA.y;
            const float wz0 = 1.f - fA.z, wz1 = fA.z;
            const float fw  = ftA * wxf;
            const int k00 = (ib + dbase) * 32 + ci;   // dz=0, dy=0 cell
            // swizzled element index: ((k>>2)^rsw)*4 + (k&3)
            #pragma unroll
            for (int dd = 0; dd < 4; ++dd) {
                const int dy = dd & 1, dz = dd >> 1;
                const int k  = k00 + dy * 128 + dz * 512;
                const float v = fw * (dz ? wz1 : wz0) * (dy ? wy1 : wy0);
                atomicAdd(&Zf[rbase + (((k >> 2) ^ rsw) << 2) + (k & 3)], v);
            }
            mA = mB; fA = fB; ftA = ftB;
            mB = mC; fB = fC;
            e += 8;
        }
    }
    __syncthreads();

    // ---------- Phase B: MFMA GEMM from LDS ----------
    // wave = (kw, nf): kw in {0,1} halves K, nf in 0..3 col-frags.
    {
        const int kw   = w >> 2;
        const int nf   = w & 3;
        const int r16  = lane & 15;
        const int kgrp = lane >> 4;
        const int rsw  = r16 & 7;
        const int rbase = r16 * KDIM;
        f32x4 acc = {0.f, 0.f, 0.f, 0.f};
        #pragma unroll 4
        for (int i = 0; i < 32; ++i) {
            const int ks = kw * 32 + i;
            const int s0 = ks * 8 + kgrp * 2;       // 16B-slot of k0=ks*32+kgrp*8
            const float4 a0 = Zf4[(rbase >> 2) + (s0 ^ rsw)];
            const float4 a1 = Zf4[(rbase >> 2) + ((s0 + 1) ^ rsw)];
            bf16x8 af;
            af[0] = (short)f2bf(a0.x); af[1] = (short)f2bf(a0.y);
            af[2] = (short)f2bf(a0.z); af[3] = (short)f2bf(a0.w);
            af[4] = (short)f2bf(a1.x); af[5] = (short)f2bf(a1.y);
            af[6] = (short)f2bf(a1.z); af[7] = (short)f2bf(a1.w);
            const bf16x8 bfg =
                *(const bf16x8*)(Wfrag + (((ks * 4 + nf) * 64) + lane) * 8);
            acc = __builtin_amdgcn_mfma_f32_16x16x32_bf16(af, bfg, acc, 0, 0, 0);
        }
        #pragma unroll
        for (int rg = 0; rg < 4; ++rg)
            partial[kw][kgrp * 4 + rg][nf * 16 + r16] = acc[rg];
    }
    __syncthreads();

    // ---------- Epilogue: reduce K-halves + dense head ----------
    #pragma unroll
    for (int rep = 0; rep < MT16 * COUT / 512; ++rep) {
        const int idx = rep * 512 + t;
        const int r = idx >> 6, o = idx & 63;
        const int q = q0 + r;
        out[q * COUT + o] = partial[0][r][o] + partial[1][r][o];
        float dacc = bd[o];
        #pragma unroll
        for (int i = 0; i < CIN; ++i)
            dacc += feats[q * CIN + i] * Wd[i * COUT + o];
        out[N_PTS * COUT + q * COUT + o] = dacc;
    }
}

// ---------------- Fallback (round-2 monolithic) if ws too small ----------
__global__ __launch_bounds__(256) void conv_dense_kernel(
    const float* __restrict__ feats, const float* __restrict__ pos,
    const float* __restrict__ Wconv, const float* __restrict__ Wd,
    const float* __restrict__ bd,
    const int* __restrict__ en, const float* __restrict__ ev,
    const int* __restrict__ qstart, int strideN,
    float* __restrict__ out)
{
    __shared__ float Z[QB][KF][CIN];
    __shared__ float partial[4][QB][COUT];
    __shared__ int   rec_n[256], rec_b[256];
    __shared__ float rec_fx[256], rec_fy[256], rec_fz[256];
    __shared__ int   qs9[QB + 1];

    const int t = threadIdx.x, wave = t >> 6, lane = t & 63;
    const int q0 = blockIdx.x * QB;
    if (t <= QB) qs9[t] = qstart[q0 + t];
    float* zf = &Z[0][0][0];
    for (int j = t; j < QB * KF * CIN; j += 256) zf[j] = 0.f;
    __syncthreads();
    const int eLo = qs9[0], eHi = qs9[QB];
    const int ci = lane & 31, dbase = lane >> 5;
    for (int cb = eLo; cb < eHi; cb += 256) {
        const int cnt = imin(256, eHi - cb);
        if (t < cnt) {
            const int e = cb + t;
            int q = q0;
            #pragma unroll
            for (int s = 1; s < QB; ++s) if (e >= qs9[s]) q = q0 + s;
            int nn = ((const int*)en)[e];   // stride folded by caller for fallback
            int ib; float fx, fy, fz;
            edge_geom(pos, nn, q, ib, fx, fy, fz);
            rec_n[t] = nn; rec_b[t] = ib;
            rec_fx[t] = fx; rec_fy[t] = fy; rec_fz[t] = fz;
        }
        __syncthreads();
        for (int s = 0; s < QB / 4; ++s) {
            const int qs = wave * (QB / 4) + s;
            const int lo = imax(qs9[qs], cb);
            const int hi = imin(qs9[qs + 1], cb + cnt);
            for (int e = lo; e < hi; ++e) {
                const int r = e - cb;
                const int n = rec_n[r], ib = rec_b[r];
                const float fx = rec_fx[r], fy = rec_fy[r], fz = rec_fz[r];
                const float fj = feats[n * CIN + ci];
                const float wxf = dbase ? fx : 1.f - fx;
                #pragma unroll
                for (int dd = 0; dd < 4; ++dd) {
                    const int dy = dd & 1, dz = dd >> 1;
                    const float w = (dz ? fz : 1.f - fz) * (dy ? fy : 1.f - fy) * wxf;
                    Z[qs][ib + dz * 16 + dy * 4 + dbase][ci] += fj * w;
                }
            }
        }
        __syncthreads();
    }
    float acc[QB];
    #pragma unroll
    for (int qs = 0; qs < QB; ++qs) acc[qs] = 0.f;
    const int o = lane;
    for (int kk = 0; kk < KF / 4; ++kk) {
        const int kf = wave * (KF / 4) + kk;
        #pragma unroll
        for (int ii = 0; ii < CIN; ii += 4) {
            float4 z4[QB];
            #pragma unroll
            for (int qs = 0; qs < QB; ++qs)
                z4[qs] = *(const float4*)&Z[qs][kf][ii];
            #pragma unroll
            for (int c = 0; c < 4; ++c) {
                const float wv = Wconv[(kf * CIN + ii + c) * COUT + o];
                #pragma unroll
                for (int qs = 0; qs < QB; ++qs)
                    acc[qs] += wv * ((const float*)&z4[qs])[c];
            }
        }
    }
    #pragma unroll
    for (int qs = 0; qs < QB; ++qs) partial[wave][qs][o] = acc[qs];
    __syncthreads();
    for (int s = 0; s < QB / 4; ++s) {
        const int qs = wave * (QB / 4) + s;
        const int q  = q0 + qs;
        out[q * COUT + o] = partial[0][qs][o] + partial[1][qs][o] +
                            partial[2][qs][o] + partial[3][qs][o];
        float dacc = bd[o];
        #pragma unroll
        for (int ii = 0; ii < CIN; ++ii)
            dacc += feats[q * CIN + ii] * Wd[ii * COUT + o];
        out[N_PTS * COUT + q * COUT + o] = dacc;
    }
}

// Repack en to int32 contiguous (for the fallback path only).
__global__ __launch_bounds__(256) void pack_en_kernel(
    const int* __restrict__ en, int stride, int* __restrict__ en32)
{
    const int e = blockIdx.x * 256 + threadIdx.x;
    if (e < E_PAD) en32[e] = en[e * stride];
}

extern "C" void kernel_launch(void* const* d_in, const int* in_sizes, int n_in,
                              void* d_out, int out_size, void* d_ws, size_t ws_size,
                              hipStream_t stream)
{
    const float* feats = (const float*)d_in[0];
    const float* pos   = (const float*)d_in[1];
    const float* Wconv = (const float*)d_in[2];
    const float* Wd    = (const float*)d_in[3];
    const float* bd    = (const float*)d_in[4];
    const int*   eq    = (const int*)d_in[5];
    const int*   en    = (const int*)d_in[6];
    const float* ev    = (const float*)d_in[7];
    const int strideQ = in_sizes[5] / E_PAD;   // int32 vs int64 hedge
    const int strideN = in_sizes[6] / E_PAD;

    int* qstart = (int*)d_ws;
    const size_t offW = 81920;                              // Wfrag (256 KB)
    const size_t offM = offW + 262144;                      // rec_m (2 MB)
    const size_t offF = offM + (size_t)E_PAD * 8;           // rec_f (4 MB)
    const size_t needed = offF + (size_t)E_PAD * 16;

    build_qstart_kernel<<<E_PAD / 256, 256, 0, stream>>>(eq, ev, strideQ, qstart);

    if (ws_size >= needed) {
        unsigned short* Wfrag = (unsigned short*)((char*)d_ws + offW);
        int2*   rec_m = (int2*)((char*)d_ws + offM);
        float4* rec_f = (float4*)((char*)d_ws + offF);
        reorder_w_kernel<<<KDIM * COUT / 256, 256, 0, stream>>>(Wconv, Wfrag);
        geom_kernel<<<E_PAD / 256, 256, 0, stream>>>(
            pos, eq, en, strideQ, strideN, rec_m, rec_f);
        fused_kernel<<<N_PTS / MT16, 512, 0, stream>>>(
            feats, Wfrag, Wd, bd, rec_m, rec_f, qstart, (float*)d_out);
    } else {
        int* en32 = (int*)((char*)d_ws + offW);   // fits in any sane ws
        pack_en_kernel<<<E_PAD / 256, 256, 0, stream>>>(en, strideN, en32);
        conv_dense_kernel<<<N_PTS / QB, 256, 0, stream>>>(
            feats, pos, Wconv, Wd, bd, en32, ev, qstart, 1, (float*)d_out);
    }
}

// Round 6
// 343.083 us; speedup vs baseline: 1.0010x; 1.0010x over previous
//
#include <hip/hip_runtime.h>

#define N_PTS 20000
#define CIN   32
#define COUT  64
#define KK    4
#define KF    64
#define KDIM  2048          // KF*CIN
#define E_PAD 262144
#define EPS   1e-12f
#define FOUR_OVER_PI 1.27323954473516f
#define QB    8             // queries per block (fallback kernel)
#define MT16  16            // queries per block (fused kernel)

typedef __attribute__((ext_vector_type(8))) short bf16x8;
typedef __attribute__((ext_vector_type(4))) float f32x4;

__device__ __forceinline__ float sgnf(float v) {
    return v > 0.f ? 1.f : (v < 0.f ? -1.f : 0.f);
}
__device__ __forceinline__ int imin(int a, int b) { return a < b ? a : b; }
__device__ __forceinline__ int imax(int a, int b) { return a > b ? a : b; }

__device__ __forceinline__ unsigned short f2bf(float f) {   // RNE f32->bf16
    unsigned u = __float_as_uint(f);
    u = u + 0x7fffu + ((u >> 16) & 1u);
    return (unsigned short)(u >> 16);
}

// ball_to_cube_volume_preserving + trilinear cell (f32, op-for-op vs ref).
__device__ __forceinline__ void edge_geom(
    const float* __restrict__ pos, int n, int q,
    int& cellb, float& ofx, float& ofy, float& ofz)
{
    const float rx = (pos[n * 3 + 0] - pos[q * 3 + 0]) * 20.f;
    const float ry = (pos[n * 3 + 1] - pos[q * 3 + 1]) * 20.f;
    const float rz = (pos[n * 3 + 2] - pos[q * 3 + 2]) * 20.f;
    const float sq   = rx * rx + ry * ry + rz * rz;
    const float nrm  = sqrtf(fmaxf(sq, EPS));
    const float rxy2 = rx * rx + ry * ry;
    const bool  top  = (1.25f * rz * rz > rxy2);
    const float s_top  = sqrtf(fmaxf(3.f * nrm / (nrm + fabsf(rz) + EPS), EPS));
    const float s_side = nrm / sqrtf(fmaxf(rxy2, EPS));
    float cx = top ? rx * s_top : rx * s_side;
    float cy = top ? ry * s_top : ry * s_side;
    float cz = top ? sgnf(rz) * nrm : 1.5f * rz;
    if (sq < EPS) { cx = 0.f; cy = 0.f; cz = 0.f; }
    const float rc2 = cx * cx + cy * cy;
    const float rxy = sqrtf(fmaxf(rc2, EPS));
    const bool  xbig = fabsf(cy) <= fabsf(cx);
    const float safe_x = (fabsf(cx) > EPS) ? cx : 1.f;
    const float safe_y = (fabsf(cy) > EPS) ? cy : 1.f;
    const float qxv = sgnf(cx) * rxy;
    const float qyv = sgnf(cy) * rxy;
    float bx = xbig ? qxv : qyv * FOUR_OVER_PI * atanf(cx / safe_y);
    float by = xbig ? qxv * FOUR_OVER_PI * atanf(cy / safe_x) : qyv;
    if (rc2 < EPS) { bx = 0.f; by = 0.f; }
    const float ux = fminf(fmaxf((bx + 1.f) * 0.5f * 3.f, 0.f), 3.f);
    const float uy = fminf(fmaxf((by + 1.f) * 0.5f * 3.f, 0.f), 3.f);
    const float uz = fminf(fmaxf((cz + 1.f) * 0.5f * 3.f, 0.f), 3.f);
    const int ix = imin(imax((int)floorf(ux), 0), 2);
    const int iy = imin(imax((int)floorf(uy), 0), 2);
    const int iz = imin(imax((int)floorf(uz), 0), 2);
    cellb = (iz * KK + iy) * KK + ix;
    ofx = ux - (float)ix; ofy = uy - (float)iy; ofz = uz - (float)iz;
}

// CSR offsets from sorted edge_q (padding keyed to N_PTS).
__global__ __launch_bounds__(256) void build_qstart_kernel(
    const int* __restrict__ eq, const float* __restrict__ ev,
    int stride, int* __restrict__ qstart)
{
    int e = blockIdx.x * 256 + threadIdx.x;
    if (e >= E_PAD) return;
    int k = (ev[e] > 0.f) ? eq[e * stride] : N_PTS;
    if (k > N_PTS) k = N_PTS;
    int kp = -1;
    if (e > 0) {
        kp = (ev[e - 1] > 0.f) ? eq[(e - 1) * stride] : N_PTS;
        if (kp > N_PTS) kp = N_PTS;
    }
    for (int q = kp + 1; q <= k; ++q) qstart[q] = e;
    if (e == E_PAD - 1) {
        for (int q = k + 1; q <= N_PTS; ++q) qstart[q] = E_PAD;
    }
}

// Per-edge geometry -> records. rec_m.y packs cell | (q << 6).
__global__ __launch_bounds__(256) void geom_kernel(
    const float* __restrict__ pos,
    const int* __restrict__ eq, const int* __restrict__ en,
    int strideQ, int strideN,
    int2* __restrict__ rec_m, float4* __restrict__ rec_f)
{
    const int e = blockIdx.x * 256 + threadIdx.x;
    if (e >= E_PAD) return;
    const int q = eq[e * strideQ];
    const int n = en[e * strideN];
    int ib; float fx, fy, fz;
    edge_geom(pos, n, q, ib, fx, fy, fz);
    rec_m[e] = make_int2(n, ib | (q << 6));
    rec_f[e] = make_float4(fx, fy, fz, 0.f);
}

// W[2048][64] f32 -> bf16 in B-fragment order: Wfrag[ks][nf][lane][j].
__global__ __launch_bounds__(256) void reorder_w_kernel(
    const float* __restrict__ Wconv, unsigned short* __restrict__ Wfrag)
{
    const int idx = blockIdx.x * 256 + threadIdx.x;   // 131072 total
    const int j    = idx & 7;
    const int lane = (idx >> 3) & 63;
    const int nf   = (idx >> 9) & 3;
    const int ks   = idx >> 11;
    const int k    = ks * 32 + ((lane >> 4) << 3) + j;
    const int col  = nf * 16 + (lane & 15);
    Wfrag[idx] = f2bf(Wconv[k * COUT + col]);
}

// Fused scatter + GEMM. 16 queries/block, Z f32 in LDS (swizzled),
// edge-parallel phase A with HW ds_add_f32 (unsafeAtomicAdd — plain
// atomicAdd on shared float compiles to a CAS loop = round-5 disaster),
// MFMA phase B from LDS.
__global__ __launch_bounds__(512, 1) void fused_kernel(
    const float* __restrict__ feats,
    const unsigned short* __restrict__ Wfrag,
    const float* __restrict__ Wd, const float* __restrict__ bd,
    const int2* __restrict__ rec_m, const float4* __restrict__ rec_f,
    const int* __restrict__ qstart, float* __restrict__ out)
{
    __shared__ float4 Zf4[MT16 * KDIM / 4];     // 128 KB, 16B aligned
    __shared__ float  partial[2][MT16][COUT];   // 8 KB
    float* Zf = (float*)Zf4;

    const int t    = threadIdx.x;
    const int w    = t >> 6;
    const int lane = t & 63;
    const int q0   = blockIdx.x * MT16;

    // zero Z (swizzle is a within-row permutation; zero everything)
    {
        const float4 z4 = {0.f, 0.f, 0.f, 0.f};
        #pragma unroll
        for (int i = 0; i < MT16 * KDIM / 4 / 512; ++i)
            Zf4[i * 512 + t] = z4;
    }
    const int e0 = qstart[q0];
    const int e1 = qstart[q0 + MT16];
    __syncthreads();

    // ---------- Phase A: edge-parallel scatter with ds_add_f32 ----------
    // lane = (ci, dbase). Wave-uniform edge index (stride 8 across waves).
    {
        const int ci    = lane & 31;
        const int dbase = lane >> 5;
        int e = e0 + w;
        int2 mA = {0, 0}, mB = {0, 0};
        float4 fA = {0, 0, 0, 0}, fB = {0, 0, 0, 0};
        float ftA = 0.f;
        if (e < e1)     { mA = rec_m[e];     fA = rec_f[e];
                          ftA = feats[(size_t)mA.x * CIN + ci]; }
        if (e + 8 < e1) { mB = rec_m[e + 8]; fB = rec_f[e + 8]; }
        while (e < e1) {
            int2 mC = {0, 0}; float4 fC = {0, 0, 0, 0}; float ftB = 0.f;
            if (e + 16 < e1) { mC = rec_m[e + 16]; fC = rec_f[e + 16]; }
            if (e + 8  < e1) { ftB = feats[(size_t)mB.x * CIN + ci]; }

            const int ib  = mA.y & 63;
            const int row = (mA.y >> 6) - q0;
            const int rsw = row & 7;
            const int rbase = row * KDIM;
            const float wxf = dbase ? fA.x : 1.f - fA.x;
            const float wy0 = 1.f - fA.y, wy1 = fA.y;
            const float wz0 = 1.f - fA.z, wz1 = fA.z;
            const float fw  = ftA * wxf;
            const int k00 = (ib + dbase) * 32 + ci;   // dz=0, dy=0 cell
            // swizzled element index: ((k>>2)^rsw)*4 + (k&3)
            #pragma unroll
            for (int dd = 0; dd < 4; ++dd) {
                const int dy = dd & 1, dz = dd >> 1;
                const int k  = k00 + dy * 128 + dz * 512;
                const float v = fw * (dz ? wz1 : wz0) * (dy ? wy1 : wy0);
                unsafeAtomicAdd(&Zf[rbase + (((k >> 2) ^ rsw) << 2) + (k & 3)], v);
            }
            mA = mB; fA = fB; ftA = ftB;
            mB = mC; fB = fC;
            e += 8;
        }
    }
    __syncthreads();

    // ---------- Phase B: MFMA GEMM from LDS ----------
    // wave = (kw, nf): kw in {0,1} halves K, nf in 0..3 col-frags.
    {
        const int kw   = w >> 2;
        const int nf   = w & 3;
        const int r16  = lane & 15;
        const int kgrp = lane >> 4;
        const int rsw  = r16 & 7;
        const int rbase = r16 * KDIM;
        f32x4 acc = {0.f, 0.f, 0.f, 0.f};
        #pragma unroll 4
        for (int i = 0; i < 32; ++i) {
            const int ks = kw * 32 + i;
            const int s0 = ks * 8 + kgrp * 2;       // 16B-slot of k0=ks*32+kgrp*8
            const float4 a0 = Zf4[(rbase >> 2) + (s0 ^ rsw)];
            const float4 a1 = Zf4[(rbase >> 2) + ((s0 + 1) ^ rsw)];
            bf16x8 af;
            af[0] = (short)f2bf(a0.x); af[1] = (short)f2bf(a0.y);
            af[2] = (short)f2bf(a0.z); af[3] = (short)f2bf(a0.w);
            af[4] = (short)f2bf(a1.x); af[5] = (short)f2bf(a1.y);
            af[6] = (short)f2bf(a1.z); af[7] = (short)f2bf(a1.w);
            const bf16x8 bfg =
                *(const bf16x8*)(Wfrag + (((ks * 4 + nf) * 64) + lane) * 8);
            acc = __builtin_amdgcn_mfma_f32_16x16x32_bf16(af, bfg, acc, 0, 0, 0);
        }
        #pragma unroll
        for (int rg = 0; rg < 4; ++rg)
            partial[kw][kgrp * 4 + rg][nf * 16 + r16] = acc[rg];
    }
    __syncthreads();

    // ---------- Epilogue: reduce K-halves + dense head ----------
    #pragma unroll
    for (int rep = 0; rep < MT16 * COUT / 512; ++rep) {
        const int idx = rep * 512 + t;
        const int r = idx >> 6, o = idx & 63;
        const int q = q0 + r;
        out[q * COUT + o] = partial[0][r][o] + partial[1][r][o];
        float dacc = bd[o];
        #pragma unroll
        for (int i = 0; i < CIN; ++i)
            dacc += feats[q * CIN + i] * Wd[i * COUT + o];
        out[N_PTS * COUT + q * COUT + o] = dacc;
    }
}

// ---------------- Fallback (round-2 monolithic) if ws too small ----------
__global__ __launch_bounds__(256) void conv_dense_kernel(
    const float* __restrict__ feats, const float* __restrict__ pos,
    const float* __restrict__ Wconv, const float* __restrict__ Wd,
    const float* __restrict__ bd,
    const int* __restrict__ en, const float* __restrict__ ev,
    const int* __restrict__ qstart, int strideN,
    float* __restrict__ out)
{
    __shared__ float Z[QB][KF][CIN];
    __shared__ float partial[4][QB][COUT];
    __shared__ int   rec_n[256], rec_b[256];
    __shared__ float rec_fx[256], rec_fy[256], rec_fz[256];
    __shared__ int   qs9[QB + 1];

    const int t = threadIdx.x, wave = t >> 6, lane = t & 63;
    const int q0 = blockIdx.x * QB;
    if (t <= QB) qs9[t] = qstart[q0 + t];
    float* zf = &Z[0][0][0];
    for (int j = t; j < QB * KF * CIN; j += 256) zf[j] = 0.f;
    __syncthreads();
    const int eLo = qs9[0], eHi = qs9[QB];
    const int ci = lane & 31, dbase = lane >> 5;
    for (int cb = eLo; cb < eHi; cb += 256) {
        const int cnt = imin(256, eHi - cb);
        if (t < cnt) {
            const int e = cb + t;
            int q = q0;
            #pragma unroll
            for (int s = 1; s < QB; ++s) if (e >= qs9[s]) q = q0 + s;
            int nn = ((const int*)en)[e];
            int ib; float fx, fy, fz;
            edge_geom(pos, nn, q, ib, fx, fy, fz);
            rec_n[t] = nn; rec_b[t] = ib;
            rec_fx[t] = fx; rec_fy[t] = fy; rec_fz[t] = fz;
        }
        __syncthreads();
        for (int s = 0; s < QB / 4; ++s) {
            const int qs = wave * (QB / 4) + s;
            const int lo = imax(qs9[qs], cb);
            const int hi = imin(qs9[qs + 1], cb + cnt);
            for (int e = lo; e < hi; ++e) {
                const int r = e - cb;
                const int n = rec_n[r], ib = rec_b[r];
                const float fx = rec_fx[r], fy = rec_fy[r], fz = rec_fz[r];
                const float fj = feats[n * CIN + ci];
                const float wxf = dbase ? fx : 1.f - fx;
                #pragma unroll
                for (int dd = 0; dd < 4; ++dd) {
                    const int dy = dd & 1, dz = dd >> 1;
                    const float w = (dz ? fz : 1.f - fz) * (dy ? fy : 1.f - fy) * wxf;
                    Z[qs][ib + dz * 16 + dy * 4 + dbase][ci] += fj * w;
                }
            }
        }
        __syncthreads();
    }
    float acc[QB];
    #pragma unroll
    for (int qs = 0; qs < QB; ++qs) acc[qs] = 0.f;
    const int o = lane;
    for (int kk = 0; kk < KF / 4; ++kk) {
        const int kf = wave * (KF / 4) + kk;
        #pragma unroll
        for (int ii = 0; ii < CIN; ii += 4) {
            float4 z4[QB];
            #pragma unroll
            for (int qs = 0; qs < QB; ++qs)
                z4[qs] = *(const float4*)&Z[qs][kf][ii];
            #pragma unroll
            for (int c = 0; c < 4; ++c) {
                const float wv = Wconv[(kf * CIN + ii + c) * COUT + o];
                #pragma unroll
                for (int qs = 0; qs < QB; ++qs)
                    acc[qs] += wv * ((const float*)&z4[qs])[c];
            }
        }
    }
    #pragma unroll
    for (int qs = 0; qs < QB; ++qs) partial[wave][qs][o] = acc[qs];
    __syncthreads();
    for (int s = 0; s < QB / 4; ++s) {
        const int qs = wave * (QB / 4) + s;
        const int q  = q0 + qs;
        out[q * COUT + o] = partial[0][qs][o] + partial[1][qs][o] +
                            partial[2][qs][o] + partial[3][qs][o];
        float dacc = bd[o];
        #pragma unroll
        for (int ii = 0; ii < CIN; ++ii)
            dacc += feats[q * CIN + ii] * Wd[ii * COUT + o];
        out[N_PTS * COUT + q * COUT + o] = dacc;
    }
}

// Repack en to int32 contiguous (for the fallback path only).
__global__ __launch_bounds__(256) void pack_en_kernel(
    const int* __restrict__ en, int stride, int* __restrict__ en32)
{
    const int e = blockIdx.x * 256 + threadIdx.x;
    if (e < E_PAD) en32[e] = en[e * stride];
}

extern "C" void kernel_launch(void* const* d_in, const int* in_sizes, int n_in,
                              void* d_out, int out_size, void* d_ws, size_t ws_size,
                              hipStream_t stream)
{
    const float* feats = (const float*)d_in[0];
    const float* pos   = (const float*)d_in[1];
    const float* Wconv = (const float*)d_in[2];
    const float* Wd    = (const float*)d_in[3];
    const float* bd    = (const float*)d_in[4];
    const int*   eq    = (const int*)d_in[5];
    const int*   en    = (const int*)d_in[6];
    const float* ev    = (const float*)d_in[7];
    const int strideQ = in_sizes[5] / E_PAD;   // int32 vs int64 hedge
    const int strideN = in_sizes[6] / E_PAD;

    int* qstart = (int*)d_ws;
    const size_t offW = 81920;                              // Wfrag (256 KB)
    const size_t offM = offW + 262144;                      // rec_m (2 MB)
    const size_t offF = offM + (size_t)E_PAD * 8;           // rec_f (4 MB)
    const size_t needed = offF + (size_t)E_PAD * 16;

    build_qstart_kernel<<<E_PAD / 256, 256, 0, stream>>>(eq, ev, strideQ, qstart);

    if (ws_size >= needed) {
        unsigned short* Wfrag = (unsigned short*)((char*)d_ws + offW);
        int2*   rec_m = (int2*)((char*)d_ws + offM);
        float4* rec_f = (float4*)((char*)d_ws + offF);
        reorder_w_kernel<<<KDIM * COUT / 256, 256, 0, stream>>>(Wconv, Wfrag);
        geom_kernel<<<E_PAD / 256, 256, 0, stream>>>(
            pos, eq, en, strideQ, strideN, rec_m, rec_f);
        fused_kernel<<<N_PTS / MT16, 512, 0, stream>>>(
            feats, Wfrag, Wd, bd, rec_m, rec_f, qstart, (float*)d_out);
    } else {
        int* en32 = (int*)((char*)d_ws + offW);
        pack_en_kernel<<<E_PAD / 256, 256, 0, stream>>>(en, strideN, en32);
        conv_dense_kernel<<<N_PTS / QB, 256, 0, stream>>>(
            feats, pos, Wconv, Wd, bd, en32, ev, qstart, 1, (float*)d_out);
    }
}

// Round 7
// 66.105 us; speedup vs baseline: 5.1953x; 5.1900x over previous
//
#include <hip/hip_runtime.h>

#define N_PTS 20000
#define CIN   32
#define COUT  64
#define KK    4
#define KF    64
#define KDIM  2048          // KF*CIN
#define E_PAD 262144
#define EPS   1e-12f
#define FOUR_OVER_PI 1.27323954473516f
#define QB    8             // queries per block (fallback kernel)
#define MT16  16            // queries per block (fused kernel)

typedef __attribute__((ext_vector_type(8))) short bf16x8;
typedef __attribute__((ext_vector_type(4))) float f32x4;

__device__ __forceinline__ float sgnf(float v) {
    return v > 0.f ? 1.f : (v < 0.f ? -1.f : 0.f);
}
__device__ __forceinline__ int imin(int a, int b) { return a < b ? a : b; }
__device__ __forceinline__ int imax(int a, int b) { return a > b ? a : b; }

__device__ __forceinline__ unsigned short f2bf(float f) {   // RNE f32->bf16
    unsigned u = __float_as_uint(f);
    u = u + 0x7fffu + ((u >> 16) & 1u);
    return (unsigned short)(u >> 16);
}

// ball_to_cube_volume_preserving + trilinear cell (f32, op-for-op vs ref).
__device__ __forceinline__ void edge_geom(
    const float* __restrict__ pos, int n, int q,
    int& cellb, float& ofx, float& ofy, float& ofz)
{
    const float rx = (pos[n * 3 + 0] - pos[q * 3 + 0]) * 20.f;
    const float ry = (pos[n * 3 + 1] - pos[q * 3 + 1]) * 20.f;
    const float rz = (pos[n * 3 + 2] - pos[q * 3 + 2]) * 20.f;
    const float sq   = rx * rx + ry * ry + rz * rz;
    const float nrm  = sqrtf(fmaxf(sq, EPS));
    const float rxy2 = rx * rx + ry * ry;
    const bool  top  = (1.25f * rz * rz > rxy2);
    const float s_top  = sqrtf(fmaxf(3.f * nrm / (nrm + fabsf(rz) + EPS), EPS));
    const float s_side = nrm / sqrtf(fmaxf(rxy2, EPS));
    float cx = top ? rx * s_top : rx * s_side;
    float cy = top ? ry * s_top : ry * s_side;
    float cz = top ? sgnf(rz) * nrm : 1.5f * rz;
    if (sq < EPS) { cx = 0.f; cy = 0.f; cz = 0.f; }
    const float rc2 = cx * cx + cy * cy;
    const float rxy = sqrtf(fmaxf(rc2, EPS));
    const bool  xbig = fabsf(cy) <= fabsf(cx);
    const float safe_x = (fabsf(cx) > EPS) ? cx : 1.f;
    const float safe_y = (fabsf(cy) > EPS) ? cy : 1.f;
    const float qxv = sgnf(cx) * rxy;
    const float qyv = sgnf(cy) * rxy;
    float bx = xbig ? qxv : qyv * FOUR_OVER_PI * atanf(cx / safe_y);
    float by = xbig ? qxv * FOUR_OVER_PI * atanf(cy / safe_x) : qyv;
    if (rc2 < EPS) { bx = 0.f; by = 0.f; }
    const float ux = fminf(fmaxf((bx + 1.f) * 0.5f * 3.f, 0.f), 3.f);
    const float uy = fminf(fmaxf((by + 1.f) * 0.5f * 3.f, 0.f), 3.f);
    const float uz = fminf(fmaxf((cz + 1.f) * 0.5f * 3.f, 0.f), 3.f);
    const int ix = imin(imax((int)floorf(ux), 0), 2);
    const int iy = imin(imax((int)floorf(uy), 0), 2);
    const int iz = imin(imax((int)floorf(uz), 0), 2);
    cellb = (iz * KK + iy) * KK + ix;
    ofx = ux - (float)ix; ofy = uy - (float)iy; ofz = uz - (float)iz;
}

// CSR offsets from sorted edge_q (padding keyed to N_PTS).
__global__ __launch_bounds__(256) void build_qstart_kernel(
    const int* __restrict__ eq, const float* __restrict__ ev,
    int stride, int* __restrict__ qstart)
{
    int e = blockIdx.x * 256 + threadIdx.x;
    if (e >= E_PAD) return;
    int k = (ev[e] > 0.f) ? eq[e * stride] : N_PTS;
    if (k > N_PTS) k = N_PTS;
    int kp = -1;
    if (e > 0) {
        kp = (ev[e - 1] > 0.f) ? eq[(e - 1) * stride] : N_PTS;
        if (kp > N_PTS) kp = N_PTS;
    }
    for (int q = kp + 1; q <= k; ++q) qstart[q] = e;
    if (e == E_PAD - 1) {
        for (int q = k + 1; q <= N_PTS; ++q) qstart[q] = E_PAD;
    }
}

// W[2048][64] f32 -> bf16 in B-fragment order: Wfrag[ks][nf][lane][j].
__global__ __launch_bounds__(256) void reorder_w_kernel(
    const float* __restrict__ Wconv, unsigned short* __restrict__ Wfrag)
{
    const int idx = blockIdx.x * 256 + threadIdx.x;   // 131072 total
    const int j    = idx & 7;
    const int lane = (idx >> 3) & 63;
    const int nf   = (idx >> 9) & 3;
    const int ks   = idx >> 11;
    const int k    = ks * 32 + ((lane >> 4) << 3) + j;
    const int col  = nf * 16 + (lane & 15);
    Wfrag[idx] = f2bf(Wconv[k * COUT + col]);
}

// Fused: per-query MFMA scatter (Z = P^T-free, edge-weights as B-operand,
// feats gathered straight into A-frags) + MFMA GEMM vs Wfrag + dense head.
// No atomics, no LDS RMW, no global Z round-trip.
__global__ __launch_bounds__(512, 1) void fused_kernel(
    const float* __restrict__ feats, const float* __restrict__ pos,
    const int* __restrict__ en, const int strideN,
    const unsigned short* __restrict__ Wfrag,
    const float* __restrict__ Wd, const float* __restrict__ bd,
    const int* __restrict__ qstart, float* __restrict__ out)
{
    __shared__ __align__(16) unsigned short Zl[MT16 * KDIM];       // 64 KB
    __shared__ __align__(16) unsigned short Pf[8][4][4][16][8];    // 32 KB
    __shared__ int   nbuf[8][32];                                  // 1 KB
    __shared__ float partial[2][MT16][COUT];                       // 8 KB
    __shared__ int   qs17[MT16 + 1];

    const int t    = threadIdx.x;
    const int w    = t >> 6;
    const int lane = t & 63;
    const int r16  = lane & 15;
    const int kgrp = lane >> 4;
    const int q0   = blockIdx.x * MT16;

    if (t <= MT16) qs17[t] = qstart[q0 + t];
    __syncthreads();

    // ---------- Phase A: per wave, 2 queries; Z via MFMA ----------
    for (int s = 0; s < 2; ++s) {
        const int qs = w * 2 + s;              // local Z row 0..15
        const int lo = qs17[qs], hi = qs17[qs + 1];
        const int nch = imax(1, (hi - lo + 31) >> 5);

        f32x4 acc[2][4];
        #pragma unroll
        for (int mf = 0; mf < 2; ++mf)
            #pragma unroll
            for (int nf = 0; nf < 4; ++nf)
                acc[mf][nf] = (f32x4){0.f, 0.f, 0.f, 0.f};

        for (int c = 0; c < nch; ++c) {
            // zero this wave's P tile (2048 shorts = 256 uint4)
            uint4* pz = (uint4*)&Pf[w][0][0][0][0];
            const uint4 z4 = {0u, 0u, 0u, 0u};
            #pragma unroll
            for (int i = 0; i < 4; ++i) pz[i * 64 + lane] = z4;

            // lanes 0..31: one edge each — geometry in parallel,
            // weights written to own B-frag column (kg = lane>>3, j = lane&7)
            if (lane < 32) {
                const int e = lo + c * 32 + lane;
                const bool v = e < hi;
                const int n = v ? en[e * strideN] : 0;
                nbuf[w][lane] = n;
                if (v) {
                    int ib; float fx, fy, fz;
                    edge_geom(pos, n, q0 + qs, ib, fx, fy, fz);
                    const int kg = lane >> 3, jj = lane & 7;
                    const float wx1 = fx, wx0 = 1.f - fx;
                    const float wy1 = fy, wy0 = 1.f - fy;
                    const float wz1 = fz, wz0 = 1.f - fz;
                    #pragma unroll
                    for (int dd = 0; dd < 8; ++dd) {
                        const int dx = dd & 1, dy = (dd >> 1) & 1, dz = dd >> 2;
                        const int cc = ib + dz * 16 + dy * 4 + dx;
                        const float wgt = (dx ? wx1 : wx0) * (dy ? wy1 : wy0) *
                                          (dz ? wz1 : wz0);
                        Pf[w][cc >> 4][kg][cc & 15][jj] = f2bf(wgt);
                    }
                }
            }
            // A-frags: gather feats for this kgrp's 8 edges (coalesced per 16)
            int nj[8];
            #pragma unroll
            for (int j = 0; j < 8; ++j) nj[j] = nbuf[w][kgrp * 8 + j];
            bf16x8 af[2];
            #pragma unroll
            for (int mf = 0; mf < 2; ++mf)
                #pragma unroll
                for (int j = 0; j < 8; ++j)
                    af[mf][j] = (short)f2bf(
                        feats[(size_t)nj[j] * CIN + mf * 16 + r16]);
            // 8 MFMA: Z[ci][cell] += F[ci][e] * P[e][cell]
            #pragma unroll
            for (int nf = 0; nf < 4; ++nf) {
                const bf16x8 bP = *(const bf16x8*)&Pf[w][nf][kgrp][r16][0];
                acc[0][nf] = __builtin_amdgcn_mfma_f32_16x16x32_bf16(
                    af[0], bP, acc[0][nf], 0, 0, 0);
                acc[1][nf] = __builtin_amdgcn_mfma_f32_16x16x32_bf16(
                    af[1], bP, acc[1][nf], 0, 0, 0);
            }
        }
        // write Z row qs as bf16, XOR-swizzled 16B slots (slot ^= row&7)
        #pragma unroll
        for (int mf = 0; mf < 2; ++mf)
            #pragma unroll
            for (int nf = 0; nf < 4; ++nf) {
                uint2 dv;
                dv.x = (unsigned)f2bf(acc[mf][nf][0]) |
                       ((unsigned)f2bf(acc[mf][nf][1]) << 16);
                dv.y = (unsigned)f2bf(acc[mf][nf][2]) |
                       ((unsigned)f2bf(acc[mf][nf][3]) << 16);
                const int k0 = (nf * 16 + r16) * 32 + mf * 16 + kgrp * 4;
                const int sl = (k0 >> 3) ^ (qs & 7);
                *(uint2*)&Zl[qs * KDIM + sl * 8 + (k0 & 7)] = dv;
            }
    }
    __syncthreads();

    // ---------- Phase B: out = Zl x Wfrag (bf16 MFMA) ----------
    {
        const int kw  = w >> 2;      // K-half
        const int nfB = w & 3;       // col-frag
        f32x4 accB = {0.f, 0.f, 0.f, 0.f};
        #pragma unroll 8
        for (int i = 0; i < 32; ++i) {
            const int ks = kw * 32 + i;
            const int sl = (ks * 4 + kgrp) ^ (r16 & 7);
            const bf16x8 a = *(const bf16x8*)&Zl[r16 * KDIM + sl * 8];
            const bf16x8 b =
                *(const bf16x8*)(Wfrag + (((ks * 4 + nfB) * 64) + lane) * 8);
            accB = __builtin_amdgcn_mfma_f32_16x16x32_bf16(a, b, accB, 0, 0, 0);
        }
        #pragma unroll
        for (int rg = 0; rg < 4; ++rg)
            partial[kw][kgrp * 4 + rg][nfB * 16 + r16] = accB[rg];
    }
    __syncthreads();

    // ---------- Epilogue: reduce K-halves + dense head ----------
    #pragma unroll
    for (int rep = 0; rep < MT16 * COUT / 512; ++rep) {
        const int idx = rep * 512 + t;
        const int r = idx >> 6, o = idx & 63;
        const int q = q0 + r;
        out[q * COUT + o] = partial[0][r][o] + partial[1][r][o];
        float dacc = bd[o];
        #pragma unroll
        for (int i = 0; i < CIN; ++i)
            dacc += feats[q * CIN + i] * Wd[i * COUT + o];
        out[N_PTS * COUT + q * COUT + o] = dacc;
    }
}

// ---------------- Fallback (round-2 monolithic) if ws too small ----------
__global__ __launch_bounds__(256) void conv_dense_kernel(
    const float* __restrict__ feats, const float* __restrict__ pos,
    const float* __restrict__ Wconv, const float* __restrict__ Wd,
    const float* __restrict__ bd,
    const int* __restrict__ en, const float* __restrict__ ev,
    const int* __restrict__ qstart, int strideN,
    float* __restrict__ out)
{
    __shared__ float Z[QB][KF][CIN];
    __shared__ float partial[4][QB][COUT];
    __shared__ int   rec_n[256], rec_b[256];
    __shared__ float rec_fx[256], rec_fy[256], rec_fz[256];
    __shared__ int   qs9[QB + 1];

    const int t = threadIdx.x, wave = t >> 6, lane = t & 63;
    const int q0 = blockIdx.x * QB;
    if (t <= QB) qs9[t] = qstart[q0 + t];
    float* zf = &Z[0][0][0];
    for (int j = t; j < QB * KF * CIN; j += 256) zf[j] = 0.f;
    __syncthreads();
    const int eLo = qs9[0], eHi = qs9[QB];
    const int ci = lane & 31, dbase = lane >> 5;
    for (int cb = eLo; cb < eHi; cb += 256) {
        const int cnt = imin(256, eHi - cb);
        if (t < cnt) {
            const int e = cb + t;
            int q = q0;
            #pragma unroll
            for (int s = 1; s < QB; ++s) if (e >= qs9[s]) q = q0 + s;
            int nn = ((const int*)en)[e];
            int ib; float fx, fy, fz;
            edge_geom(pos, nn, q, ib, fx, fy, fz);
            rec_n[t] = nn; rec_b[t] = ib;
            rec_fx[t] = fx; rec_fy[t] = fy; rec_fz[t] = fz;
        }
        __syncthreads();
        for (int s = 0; s < QB / 4; ++s) {
            const int qs = wave * (QB / 4) + s;
            const int lo = imax(qs9[qs], cb);
            const int hi = imin(qs9[qs + 1], cb + cnt);
            for (int e = lo; e < hi; ++e) {
                const int r = e - cb;
                const int n = rec_n[r], ib = rec_b[r];
                const float fx = rec_fx[r], fy = rec_fy[r], fz = rec_fz[r];
                const float fj = feats[n * CIN + ci];
                const float wxf = dbase ? fx : 1.f - fx;
                #pragma unroll
                for (int dd = 0; dd < 4; ++dd) {
                    const int dy = dd & 1, dz = dd >> 1;
                    const float wv = (dz ? fz : 1.f - fz) * (dy ? fy : 1.f - fy) * wxf;
                    Z[qs][ib + dz * 16 + dy * 4 + dbase][ci] += fj * wv;
                }
            }
        }
        __syncthreads();
    }
    float acc[QB];
    #pragma unroll
    for (int qs = 0; qs < QB; ++qs) acc[qs] = 0.f;
    const int o = lane;
    for (int kk = 0; kk < KF / 4; ++kk) {
        const int kf = wave * (KF / 4) + kk;
        #pragma unroll
        for (int ii = 0; ii < CIN; ii += 4) {
            float4 z4[QB];
            #pragma unroll
            for (int qs = 0; qs < QB; ++qs)
                z4[qs] = *(const float4*)&Z[qs][kf][ii];
            #pragma unroll
            for (int c = 0; c < 4; ++c) {
                const float wv = Wconv[(kf * CIN + ii + c) * COUT + o];
                #pragma unroll
                for (int qs = 0; qs < QB; ++qs)
                    acc[qs] += wv * ((const float*)&z4[qs])[c];
            }
        }
    }
    #pragma unroll
    for (int qs = 0; qs < QB; ++qs) partial[wave][qs][o] = acc[qs];
    __syncthreads();
    for (int s = 0; s < QB / 4; ++s) {
        const int qs = wave * (QB / 4) + s;
        const int q  = q0 + qs;
        out[q * COUT + o] = partial[0][qs][o] + partial[1][qs][o] +
                            partial[2][qs][o] + partial[3][qs][o];
        float dacc = bd[o];
        #pragma unroll
        for (int ii = 0; ii < CIN; ++ii)
            dacc += feats[q * CIN + ii] * Wd[ii * COUT + o];
        out[N_PTS * COUT + q * COUT + o] = dacc;
    }
}

// Repack en to int32 contiguous (fallback path only).
__global__ __launch_bounds__(256) void pack_en_kernel(
    const int* __restrict__ en, int stride, int* __restrict__ en32)
{
    const int e = blockIdx.x * 256 + threadIdx.x;
    if (e < E_PAD) en32[e] = en[e * stride];
}

extern "C" void kernel_launch(void* const* d_in, const int* in_sizes, int n_in,
                              void* d_out, int out_size, void* d_ws, size_t ws_size,
                              hipStream_t stream)
{
    const float* feats = (const float*)d_in[0];
    const float* pos   = (const float*)d_in[1];
    const float* Wconv = (const float*)d_in[2];
    const float* Wd    = (const float*)d_in[3];
    const float* bd    = (const float*)d_in[4];
    const int*   eq    = (const int*)d_in[5];
    const int*   en    = (const int*)d_in[6];
    const float* ev    = (const float*)d_in[7];
    const int strideQ = in_sizes[5] / E_PAD;   // int32 vs int64 hedge
    const int strideN = in_sizes[6] / E_PAD;

    int* qstart = (int*)d_ws;
    const size_t offW = 81920;                 // Wfrag (256 KB) after qstart
    const size_t needed = offW + 262144;

    build_qstart_kernel<<<E_PAD / 256, 256, 0, stream>>>(eq, ev, strideQ, qstart);

    if (ws_size >= needed) {
        unsigned short* Wfrag = (unsigned short*)((char*)d_ws + offW);
        reorder_w_kernel<<<KDIM * COUT / 256, 256, 0, stream>>>(Wconv, Wfrag);
        fused_kernel<<<N_PTS / MT16, 512, 0, stream>>>(
            feats, pos, en, strideN, Wfrag, Wd, bd, qstart, (float*)d_out);
    } else {
        int* en32 = (int*)((char*)d_ws + offW);
        pack_en_kernel<<<E_PAD / 256, 256, 0, stream>>>(en, strideN, en32);
        conv_dense_kernel<<<N_PTS / QB, 256, 0, stream>>>(
            feats, pos, Wconv, Wd, bd, en32, ev, qstart, 1, (float*)d_out);
    }
}

// Round 8
// 59.123 us; speedup vs baseline: 5.8088x; 1.1181x over previous
//
#include <hip/hip_runtime.h>

#define N_PTS 20000
#define CIN   32
#define COUT  64
#define KK    4
#define KF    64
#define KDIM  2048          // KF*CIN
#define E_PAD 262144
#define EPS   1e-12f
#define FOUR_OVER_PI 1.27323954473516f
#define QB    8             // queries per block (fallback kernel)
#define MT16  16            // queries per block (fused kernel)

typedef __attribute__((ext_vector_type(8))) short bf16x8;
typedef __attribute__((ext_vector_type(4))) float f32x4;

__device__ __forceinline__ float sgnf(float v) {
    return v > 0.f ? 1.f : (v < 0.f ? -1.f : 0.f);
}
__device__ __forceinline__ int imin(int a, int b) { return a < b ? a : b; }
__device__ __forceinline__ int imax(int a, int b) { return a > b ? a : b; }

__device__ __forceinline__ unsigned short f2bf(float f) {   // RNE f32->bf16
    unsigned u = __float_as_uint(f);
    u = u + 0x7fffu + ((u >> 16) & 1u);
    return (unsigned short)(u >> 16);
}

// ball_to_cube_volume_preserving + trilinear cell (f32, op-for-op vs ref).
__device__ __forceinline__ void edge_geom(
    const float* __restrict__ pos, int n, int q,
    int& cellb, float& ofx, float& ofy, float& ofz)
{
    const float rx = (pos[n * 3 + 0] - pos[q * 3 + 0]) * 20.f;
    const float ry = (pos[n * 3 + 1] - pos[q * 3 + 1]) * 20.f;
    const float rz = (pos[n * 3 + 2] - pos[q * 3 + 2]) * 20.f;
    const float sq   = rx * rx + ry * ry + rz * rz;
    const float nrm  = sqrtf(fmaxf(sq, EPS));
    const float rxy2 = rx * rx + ry * ry;
    const bool  top  = (1.25f * rz * rz > rxy2);
    const float s_top  = sqrtf(fmaxf(3.f * nrm / (nrm + fabsf(rz) + EPS), EPS));
    const float s_side = nrm / sqrtf(fmaxf(rxy2, EPS));
    float cx = top ? rx * s_top : rx * s_side;
    float cy = top ? ry * s_top : ry * s_side;
    float cz = top ? sgnf(rz) * nrm : 1.5f * rz;
    if (sq < EPS) { cx = 0.f; cy = 0.f; cz = 0.f; }
    const float rc2 = cx * cx + cy * cy;
    const float rxy = sqrtf(fmaxf(rc2, EPS));
    const bool  xbig = fabsf(cy) <= fabsf(cx);
    const float safe_x = (fabsf(cx) > EPS) ? cx : 1.f;
    const float safe_y = (fabsf(cy) > EPS) ? cy : 1.f;
    const float qxv = sgnf(cx) * rxy;
    const float qyv = sgnf(cy) * rxy;
    float bx = xbig ? qxv : qyv * FOUR_OVER_PI * atanf(cx / safe_y);
    float by = xbig ? qxv * FOUR_OVER_PI * atanf(cy / safe_x) : qyv;
    if (rc2 < EPS) { bx = 0.f; by = 0.f; }
    const float ux = fminf(fmaxf((bx + 1.f) * 0.5f * 3.f, 0.f), 3.f);
    const float uy = fminf(fmaxf((by + 1.f) * 0.5f * 3.f, 0.f), 3.f);
    const float uz = fminf(fmaxf((cz + 1.f) * 0.5f * 3.f, 0.f), 3.f);
    const int ix = imin(imax((int)floorf(ux), 0), 2);
    const int iy = imin(imax((int)floorf(uy), 0), 2);
    const int iz = imin(imax((int)floorf(uz), 0), 2);
    cellb = (iz * KK + iy) * KK + ix;
    ofx = ux - (float)ix; ofy = uy - (float)iy; ofz = uz - (float)iz;
}

// CSR offsets from sorted edge_q (padding keyed to N_PTS).
__global__ __launch_bounds__(256) void build_qstart_kernel(
    const int* __restrict__ eq, const float* __restrict__ ev,
    int stride, int* __restrict__ qstart)
{
    int e = blockIdx.x * 256 + threadIdx.x;
    if (e >= E_PAD) return;
    int k = (ev[e] > 0.f) ? eq[e * stride] : N_PTS;
    if (k > N_PTS) k = N_PTS;
    int kp = -1;
    if (e > 0) {
        kp = (ev[e - 1] > 0.f) ? eq[(e - 1) * stride] : N_PTS;
        if (kp > N_PTS) kp = N_PTS;
    }
    for (int q = kp + 1; q <= k; ++q) qstart[q] = e;
    if (e == E_PAD - 1) {
        for (int q = k + 1; q <= N_PTS; ++q) qstart[q] = E_PAD;
    }
}

// W[2048][64] f32 -> bf16 in B-fragment order: Wfrag[ks][nf][lane][j].
__global__ __launch_bounds__(256) void reorder_w_kernel(
    const float* __restrict__ Wconv, unsigned short* __restrict__ Wfrag)
{
    const int idx = blockIdx.x * 256 + threadIdx.x;   // 131072 total
    const int j    = idx & 7;
    const int lane = (idx >> 3) & 63;
    const int nf   = (idx >> 9) & 3;
    const int ks   = idx >> 11;
    const int k    = ks * 32 + ((lane >> 4) << 3) + j;
    const int col  = nf * 16 + (lane & 15);
    Wfrag[idx] = f2bf(Wconv[k * COUT + col]);
}

// Fused: per-query MFMA scatter (edge weights built IN REGISTERS from a
// tiny per-wave record buffer — no P tile, no LDS atomics, no RMW) +
// MFMA GEMM vs Wfrag + dense head.
// Zl layout: 16B slot = (k>>5)*64 + row*4 + ((k>>3)&3), stored slot
// XOR'd by ((slot>>6)&7): phase-B reads are 64 consecutive slots (1 KB
// contiguous per instr = conflict-free); writes spread ~4/bank.
__global__ __launch_bounds__(512, 4) void fused_kernel(
    const float* __restrict__ feats, const float* __restrict__ pos,
    const int* __restrict__ en, const int strideN,
    const unsigned short* __restrict__ Wfrag,
    const float* __restrict__ Wd, const float* __restrict__ bd,
    const int* __restrict__ qstart, float* __restrict__ out)
{
    __shared__ __align__(16) unsigned short Zl[MT16 * KDIM];   // 64 KB
    __shared__ float4 ebuf[8][32];                             // 4 KB
    __shared__ float  partial[2][MT16][COUT];                  // 8 KB
    __shared__ int    qs17[MT16 + 1];

    const int t    = threadIdx.x;
    const int w    = t >> 6;
    const int lane = t & 63;
    const int r16  = lane & 15;
    const int kgrp = lane >> 4;
    const int q0   = blockIdx.x * MT16;

    if (t <= MT16) qs17[t] = qstart[q0 + t];
    __syncthreads();

    // ---------- Phase A: per wave, 2 queries; Z via MFMA ----------
    const int dxc = r16 & 3, dyc = r16 >> 2;   // this lane's cell coords
    for (int s = 0; s < 2; ++s) {
        const int qs = w * 2 + s;              // local Z row 0..15
        const int lo = qs17[qs], hi = qs17[qs + 1];
        const int nch = imax(1, (hi - lo + 31) >> 5);

        f32x4 acc[2][4];
        #pragma unroll
        for (int mf = 0; mf < 2; ++mf)
            #pragma unroll
            for (int nf = 0; nf < 4; ++nf)
                acc[mf][nf] = (f32x4){0.f, 0.f, 0.f, 0.f};

        for (int c = 0; c < nch; ++c) {
            // lanes 0..31: one edge each — geometry computed once,
            // 16B record broadcast via LDS (wave-synchronous).
            if (lane < 32) {
                const int e = lo + c * 32 + lane;
                const bool v = e < hi;
                int n = 0, ib = 0;
                float fx = 0.f, fy = 0.f, fz = 0.f;
                if (v) {
                    n = en[e * strideN];
                    edge_geom(pos, n, q0 + qs, ib, fx, fy, fz);
                }
                float4 r;
                r.x = fx; r.y = fy; r.z = fz;
                r.w = __int_as_float(n | (ib << 16) | (v ? (1 << 22) : 0));
                ebuf[w][lane] = r;
            }
            // all 64 lanes: build A (feats gather) and B (weights) frags.
            bf16x8 bP[4], af[2];
            #pragma unroll
            for (int j = 0; j < 8; ++j) {
                const float4 r = ebuf[w][kgrp * 8 + j];
                const int   meta = __float_as_int(r.w);
                const int   n    = meta & 0xFFFF;
                const int   ib   = (meta >> 16) & 63;
                const float valid = (meta & (1 << 22)) ? 1.f : 0.f;
                const int ix = ib & 3, iy = (ib >> 2) & 3, iz = ib >> 4;
                const float wx = (dxc == ix) ? (1.f - r.x)
                               : ((dxc == ix + 1) ? r.x : 0.f);
                const float wy = (dyc == iy) ? (1.f - r.y)
                               : ((dyc == iy + 1) ? r.y : 0.f);
                const float wxy = wx * wy * valid;
                #pragma unroll
                for (int nf = 0; nf < 4; ++nf) {
                    const float wz = (nf == iz) ? (1.f - r.z)
                                   : ((nf == iz + 1) ? r.z : 0.f);
                    bP[nf][j] = (short)f2bf(wxy * wz);
                }
                af[0][j] = (short)f2bf(feats[(size_t)n * CIN + r16]);
                af[1][j] = (short)f2bf(feats[(size_t)n * CIN + 16 + r16]);
            }
            #pragma unroll
            for (int nf = 0; nf < 4; ++nf) {
                acc[0][nf] = __builtin_amdgcn_mfma_f32_16x16x32_bf16(
                    af[0], bP[nf], acc[0][nf], 0, 0, 0);
                acc[1][nf] = __builtin_amdgcn_mfma_f32_16x16x32_bf16(
                    af[1], bP[nf], acc[1][nf], 0, 0, 0);
            }
        }
        // write Z row qs as bf16 into swizzled Zl.
        // k = (nf*16+r16)*32 + mf*16 + kgrp*4 + rg
        #pragma unroll
        for (int mf = 0; mf < 2; ++mf)
            #pragma unroll
            for (int nf = 0; nf < 4; ++nf) {
                uint2 dv;
                dv.x = (unsigned)f2bf(acc[mf][nf][0]) |
                       ((unsigned)f2bf(acc[mf][nf][1]) << 16);
                dv.y = (unsigned)f2bf(acc[mf][nf][2]) |
                       ((unsigned)f2bf(acc[mf][nf][3]) << 16);
                const int g      = nf * 16 + r16;                 // k>>5
                const int slot   = g * 64 + qs * 4 + mf * 2 + (kgrp >> 1);
                const int stored = slot ^ (g & 7);
                *(uint2*)&Zl[stored * 8 + (kgrp & 1) * 4] = dv;
            }
    }
    __syncthreads();

    // ---------- Phase B: out = Zl x Wfrag (bf16 MFMA) ----------
    {
        const int kw  = w >> 2;      // K-half
        const int nfB = w & 3;       // col-frag
        f32x4 accB = {0.f, 0.f, 0.f, 0.f};
        #pragma unroll 8
        for (int i = 0; i < 32; ++i) {
            const int ks = kw * 32 + i;
            const int stored = (ks * 64 + r16 * 4 + kgrp) ^ (ks & 7);
            const bf16x8 a = *(const bf16x8*)&Zl[stored * 8];
            const bf16x8 b =
                *(const bf16x8*)(Wfrag + (((ks * 4 + nfB) * 64) + lane) * 8);
            accB = __builtin_amdgcn_mfma_f32_16x16x32_bf16(a, b, accB, 0, 0, 0);
        }
        #pragma unroll
        for (int rg = 0; rg < 4; ++rg)
            partial[kw][kgrp * 4 + rg][nfB * 16 + r16] = accB[rg];
    }
    __syncthreads();

    // ---------- Epilogue: reduce K-halves + dense head ----------
    #pragma unroll
    for (int rep = 0; rep < MT16 * COUT / 512; ++rep) {
        const int idx = rep * 512 + t;
        const int r = idx >> 6, o = idx & 63;
        const int q = q0 + r;
        out[q * COUT + o] = partial[0][r][o] + partial[1][r][o];
        float dacc = bd[o];
        #pragma unroll
        for (int i = 0; i < CIN; ++i)
            dacc += feats[q * CIN + i] * Wd[i * COUT + o];
        out[N_PTS * COUT + q * COUT + o] = dacc;
    }
}

// ---------------- Fallback (round-2 monolithic) if ws too small ----------
__global__ __launch_bounds__(256) void conv_dense_kernel(
    const float* __restrict__ feats, const float* __restrict__ pos,
    const float* __restrict__ Wconv, const float* __restrict__ Wd,
    const float* __restrict__ bd,
    const int* __restrict__ en, const float* __restrict__ ev,
    const int* __restrict__ qstart, int strideN,
    float* __restrict__ out)
{
    __shared__ float Z[QB][KF][CIN];
    __shared__ float partial[4][QB][COUT];
    __shared__ int   rec_n[256], rec_b[256];
    __shared__ float rec_fx[256], rec_fy[256], rec_fz[256];
    __shared__ int   qs9[QB + 1];

    const int t = threadIdx.x, wave = t >> 6, lane = t & 63;
    const int q0 = blockIdx.x * QB;
    if (t <= QB) qs9[t] = qstart[q0 + t];
    float* zf = &Z[0][0][0];
    for (int j = t; j < QB * KF * CIN; j += 256) zf[j] = 0.f;
    __syncthreads();
    const int eLo = qs9[0], eHi = qs9[QB];
    const int ci = lane & 31, dbase = lane >> 5;
    for (int cb = eLo; cb < eHi; cb += 256) {
        const int cnt = imin(256, eHi - cb);
        if (t < cnt) {
            const int e = cb + t;
            int q = q0;
            #pragma unroll
            for (int s = 1; s < QB; ++s) if (e >= qs9[s]) q = q0 + s;
            int nn = ((const int*)en)[e];
            int ib; float fx, fy, fz;
            edge_geom(pos, nn, q, ib, fx, fy, fz);
            rec_n[t] = nn; rec_b[t] = ib;
            rec_fx[t] = fx; rec_fy[t] = fy; rec_fz[t] = fz;
        }
        __syncthreads();
        for (int s = 0; s < QB / 4; ++s) {
            const int qs = wave * (QB / 4) + s;
            const int lo = imax(qs9[qs], cb);
            const int hi = imin(qs9[qs + 1], cb + cnt);
            for (int e = lo; e < hi; ++e) {
                const int r = e - cb;
                const int n = rec_n[r], ib = rec_b[r];
                const float fx = rec_fx[r], fy = rec_fy[r], fz = rec_fz[r];
                const float fj = feats[n * CIN + ci];
                const float wxf = dbase ? fx : 1.f - fx;
                #pragma unroll
                for (int dd = 0; dd < 4; ++dd) {
                    const int dy = dd & 1, dz = dd >> 1;
                    const float wv = (dz ? fz : 1.f - fz) * (dy ? fy : 1.f - fy) * wxf;
                    Z[qs][ib + dz * 16 + dy * 4 + dbase][ci] += fj * wv;
                }
            }
        }
        __syncthreads();
    }
    float acc[QB];
    #pragma unroll
    for (int qs = 0; qs < QB; ++qs) acc[qs] = 0.f;
    const int o = lane;
    for (int kk = 0; kk < KF / 4; ++kk) {
        const int kf = wave * (KF / 4) + kk;
        #pragma unroll
        for (int ii = 0; ii < CIN; ii += 4) {
            float4 z4[QB];
            #pragma unroll
            for (int qs = 0; qs < QB; ++qs)
                z4[qs] = *(const float4*)&Z[qs][kf][ii];
            #pragma unroll
            for (int c = 0; c < 4; ++c) {
                const float wv = Wconv[(kf * CIN + ii + c) * COUT + o];
                #pragma unroll
                for (int qs = 0; qs < QB; ++qs)
                    acc[qs] += wv * ((const float*)&z4[qs])[c];
            }
        }
    }
    #pragma unroll
    for (int qs = 0; qs < QB; ++qs) partial[wave][qs][o] = acc[qs];
    __syncthreads();
    for (int s = 0; s < QB / 4; ++s) {
        const int qs = wave * (QB / 4) + s;
        const int q  = q0 + qs;
        out[q * COUT + o] = partial[0][qs][o] + partial[1][qs][o] +
                            partial[2][qs][o] + partial[3][qs][o];
        float dacc = bd[o];
        #pragma unroll
        for (int ii = 0; ii < CIN; ++ii)
            dacc += feats[q * CIN + ii] * Wd[ii * COUT + o];
        out[N_PTS * COUT + q * COUT + o] = dacc;
    }
}

// Repack en to int32 contiguous (fallback path only).
__global__ __launch_bounds__(256) void pack_en_kernel(
    const int* __restrict__ en, int stride, int* __restrict__ en32)
{
    const int e = blockIdx.x * 256 + threadIdx.x;
    if (e < E_PAD) en32[e] = en[e * stride];
}

extern "C" void kernel_launch(void* const* d_in, const int* in_sizes, int n_in,
                              void* d_out, int out_size, void* d_ws, size_t ws_size,
                              hipStream_t stream)
{
    const float* feats = (const float*)d_in[0];
    const float* pos   = (const float*)d_in[1];
    const float* Wconv = (const float*)d_in[2];
    const float* Wd    = (const float*)d_in[3];
    const float* bd    = (const float*)d_in[4];
    const int*   eq    = (const int*)d_in[5];
    const int*   en    = (const int*)d_in[6];
    const float* ev    = (const float*)d_in[7];
    const int strideQ = in_sizes[5] / E_PAD;   // int32 vs int64 hedge
    const int strideN = in_sizes[6] / E_PAD;

    int* qstart = (int*)d_ws;
    const size_t offW = 81920;                 // Wfrag (256 KB) after qstart
    const size_t needed = offW + 262144;

    build_qstart_kernel<<<E_PAD / 256, 256, 0, stream>>>(eq, ev, strideQ, qstart);

    if (ws_size >= needed) {
        unsigned short* Wfrag = (unsigned short*)((char*)d_ws + offW);
        reorder_w_kernel<<<KDIM * COUT / 256, 256, 0, stream>>>(Wconv, Wfrag);
        fused_kernel<<<N_PTS / MT16, 512, 0, stream>>>(
            feats, pos, en, strideN, Wfrag, Wd, bd, qstart, (float*)d_out);
    } else {
        int* en32 = (int*)((char*)d_ws + offW);
        pack_en_kernel<<<E_PAD / 256, 256, 0, stream>>>(en, strideN, en32);
        conv_dense_kernel<<<N_PTS / QB, 256, 0, stream>>>(
            feats, pos, Wconv, Wd, bd, en32, ev, qstart, 1, (float*)d_out);
    }
}

// Round 9
// 53.556 us; speedup vs baseline: 6.4126x; 1.1040x over previous
//
#include <hip/hip_runtime.h>

#define N_PTS 20000
#define CIN   32
#define COUT  64
#define KK    4
#define KF    64
#define KDIM  2048          // KF*CIN
#define E_PAD 262144
#define EPS   1e-12f
#define FOUR_OVER_PI 1.27323954473516f
#define QB    8             // queries per block (fallback kernel)
#define MT16  16            // queries per block (fused kernel)

typedef __attribute__((ext_vector_type(8))) short bf16x8;
typedef __attribute__((ext_vector_type(4))) float f32x4;

__device__ __forceinline__ float sgnf(float v) {
    return v > 0.f ? 1.f : (v < 0.f ? -1.f : 0.f);
}
__device__ __forceinline__ int imin(int a, int b) { return a < b ? a : b; }
__device__ __forceinline__ int imax(int a, int b) { return a > b ? a : b; }

__device__ __forceinline__ unsigned short f2bf(float f) {   // RNE f32->bf16
    unsigned u = __float_as_uint(f);
    u = u + 0x7fffu + ((u >> 16) & 1u);
    return (unsigned short)(u >> 16);
}

// HW packed conversion: lo16 = bf16(a), hi16 = bf16(b), RNE.
__device__ __forceinline__ unsigned cvtpk(float a, float b) {
    unsigned r;
    asm("v_cvt_pk_bf16_f32 %0, %1, %2" : "=v"(r) : "v"(a), "v"(b));
    return r;
}

// ball_to_cube_volume_preserving + trilinear cell (f32, op-for-op vs ref).
__device__ __forceinline__ void edge_geom(
    const float* __restrict__ pos, int n, int q,
    int& cellb, float& ofx, float& ofy, float& ofz)
{
    const float rx = (pos[n * 3 + 0] - pos[q * 3 + 0]) * 20.f;
    const float ry = (pos[n * 3 + 1] - pos[q * 3 + 1]) * 20.f;
    const float rz = (pos[n * 3 + 2] - pos[q * 3 + 2]) * 20.f;
    const float sq   = rx * rx + ry * ry + rz * rz;
    const float nrm  = sqrtf(fmaxf(sq, EPS));
    const float rxy2 = rx * rx + ry * ry;
    const bool  top  = (1.25f * rz * rz > rxy2);
    const float s_top  = sqrtf(fmaxf(3.f * nrm / (nrm + fabsf(rz) + EPS), EPS));
    const float s_side = nrm / sqrtf(fmaxf(rxy2, EPS));
    float cx = top ? rx * s_top : rx * s_side;
    float cy = top ? ry * s_top : ry * s_side;
    float cz = top ? sgnf(rz) * nrm : 1.5f * rz;
    if (sq < EPS) { cx = 0.f; cy = 0.f; cz = 0.f; }
    const float rc2 = cx * cx + cy * cy;
    const float rxy = sqrtf(fmaxf(rc2, EPS));
    const bool  xbig = fabsf(cy) <= fabsf(cx);
    const float safe_x = (fabsf(cx) > EPS) ? cx : 1.f;
    const float safe_y = (fabsf(cy) > EPS) ? cy : 1.f;
    const float qxv = sgnf(cx) * rxy;
    const float qyv = sgnf(cy) * rxy;
    float bx = xbig ? qxv : qyv * FOUR_OVER_PI * atanf(cx / safe_y);
    float by = xbig ? qxv * FOUR_OVER_PI * atanf(cy / safe_x) : qyv;
    if (rc2 < EPS) { bx = 0.f; by = 0.f; }
    const float ux = fminf(fmaxf((bx + 1.f) * 0.5f * 3.f, 0.f), 3.f);
    const float uy = fminf(fmaxf((by + 1.f) * 0.5f * 3.f, 0.f), 3.f);
    const float uz = fminf(fmaxf((cz + 1.f) * 0.5f * 3.f, 0.f), 3.f);
    const int ix = imin(imax((int)floorf(ux), 0), 2);
    const int iy = imin(imax((int)floorf(uy), 0), 2);
    const int iz = imin(imax((int)floorf(uz), 0), 2);
    cellb = (iz * KK + iy) * KK + ix;
    ofx = ux - (float)ix; ofy = uy - (float)iy; ofz = uz - (float)iz;
}

// CSR offsets from sorted edge_q (padding keyed to N_PTS).
__global__ __launch_bounds__(256) void build_qstart_kernel(
    const int* __restrict__ eq, const float* __restrict__ ev,
    int stride, int* __restrict__ qstart)
{
    int e = blockIdx.x * 256 + threadIdx.x;
    if (e >= E_PAD) return;
    int k = (ev[e] > 0.f) ? eq[e * stride] : N_PTS;
    if (k > N_PTS) k = N_PTS;
    int kp = -1;
    if (e > 0) {
        kp = (ev[e - 1] > 0.f) ? eq[(e - 1) * stride] : N_PTS;
        if (kp > N_PTS) kp = N_PTS;
    }
    for (int q = kp + 1; q <= k; ++q) qstart[q] = e;
    if (e == E_PAD - 1) {
        for (int q = k + 1; q <= N_PTS; ++q) qstart[q] = E_PAD;
    }
}

// W[2048][64] f32 -> bf16 in B-fragment order: Wfrag[ks][nf][lane][j].
__global__ __launch_bounds__(256) void reorder_w_kernel(
    const float* __restrict__ Wconv, unsigned short* __restrict__ Wfrag)
{
    const int idx = blockIdx.x * 256 + threadIdx.x;   // 131072 total
    const int j    = idx & 7;
    const int lane = (idx >> 3) & 63;
    const int nf   = (idx >> 9) & 3;
    const int ks   = idx >> 11;
    const int k    = ks * 32 + ((lane >> 4) << 3) + j;
    const int col  = nf * 16 + (lane & 15);
    Wfrag[idx] = f2bf(Wconv[k * COUT + col]);
}

// feats f32 -> bf16 (pair-packed), one-time.
__global__ __launch_bounds__(256) void feats_bf16_kernel(
    const float* __restrict__ feats, unsigned* __restrict__ fb)
{
    const int i = blockIdx.x * 256 + threadIdx.x;   // N_PTS*CIN/2 total
    if (i < N_PTS * CIN / 2)
        fb[i] = cvtpk(feats[2 * i], feats[2 * i + 1]);
}

// Per-edge geometry -> 16B records (edge-parallel, 100% lane util).
// rec = {fx, fy, fz, meta = n | ib<<16 | 1<<22}.
__global__ __launch_bounds__(256) void geom_kernel(
    const float* __restrict__ pos,
    const int* __restrict__ eq, const int* __restrict__ en,
    int strideQ, int strideN, float4* __restrict__ rec)
{
    const int e = blockIdx.x * 256 + threadIdx.x;
    if (e >= E_PAD) return;
    const int q = eq[e * strideQ];
    const int n = en[e * strideN];
    int ib; float fx, fy, fz;
    edge_geom(pos, n, q, ib, fx, fy, fz);
    float4 r;
    r.x = fx; r.y = fy; r.z = fz;
    r.w = __int_as_float(n | (ib << 16) | (1 << 22));
    rec[e] = r;
}

// Fused: per-query MFMA scatter (weights built in registers from records,
// HW cvt_pk packing, bf16 feats gather) + MFMA GEMM vs Wfrag + dense head.
__global__ __launch_bounds__(512, 4) void fused_kernel(
    const float* __restrict__ feats, const unsigned short* __restrict__ fb16,
    const float4* __restrict__ rec,
    const unsigned short* __restrict__ Wfrag,
    const float* __restrict__ Wd, const float* __restrict__ bd,
    const int* __restrict__ qstart, float* __restrict__ out)
{
    __shared__ __align__(16) unsigned short Zl[MT16 * KDIM];   // 64 KB
    __shared__ float4 ebuf[8][32];                             // 4 KB
    __shared__ float  partial[2][MT16][COUT];                  // 8 KB
    __shared__ int    qs17[MT16 + 1];

    const int t    = threadIdx.x;
    const int w    = t >> 6;
    const int lane = t & 63;
    const int r16  = lane & 15;
    const int kgrp = lane >> 4;
    const int q0   = blockIdx.x * MT16;

    if (t <= MT16) qs17[t] = qstart[q0 + t];
    __syncthreads();

    // ---------- Phase A: per wave, 2 queries; Z via MFMA ----------
    const int dxc = r16 & 3, dyc = r16 >> 2;   // this lane's cell coords
    for (int s = 0; s < 2; ++s) {
        const int qs = w * 2 + s;              // local Z row 0..15
        const int lo = qs17[qs], hi = qs17[qs + 1];
        const int nch = imax(1, (hi - lo + 31) >> 5);

        f32x4 acc[2][4];
        #pragma unroll
        for (int mf = 0; mf < 2; ++mf)
            #pragma unroll
            for (int nf = 0; nf < 4; ++nf)
                acc[mf][nf] = (f32x4){0.f, 0.f, 0.f, 0.f};

        for (int c = 0; c < nch; ++c) {
            // lanes 0..31: stage one record each (wave-synchronous).
            if (lane < 32) {
                const int e = lo + c * 32 + lane;
                float4 r;
                if (e < hi) r = rec[e];
                else { r.x = 0.f; r.y = 0.f; r.z = 0.f;
                       r.w = __int_as_float(0); }    // meta=0 -> valid=0
                ebuf[w][lane] = r;
            }
            // all lanes: build B (weights, pair-packed) and A (bf16 gather).
            bf16x8 bP[4], af[2];
            #pragma unroll
            for (int jp = 0; jp < 4; ++jp) {
                float p[2][4];
                #pragma unroll
                for (int h = 0; h < 2; ++h) {
                    const int j = jp * 2 + h;
                    const float4 r = ebuf[w][kgrp * 8 + j];
                    const int meta = __float_as_int(r.w);
                    const int n    = meta & 0xFFFF;
                    const int ib   = (meta >> 16) & 63;
                    const float valid = (meta & (1 << 22)) ? 1.f : 0.f;
                    const int ix = ib & 3, iy = (ib >> 2) & 3, iz = ib >> 4;
                    const float wx = (dxc == ix) ? (1.f - r.x)
                                   : ((dxc == ix + 1) ? r.x : 0.f);
                    const float wy = (dyc == iy) ? (1.f - r.y)
                                   : ((dyc == iy + 1) ? r.y : 0.f);
                    const float wxy = wx * wy * valid;
                    const float z0 = wxy * (1.f - r.z), z1 = wxy * r.z;
                    p[h][0] = (iz == 0) ? z0 : 0.f;
                    p[h][1] = (iz == 0) ? z1 : ((iz == 1) ? z0 : 0.f);
                    p[h][2] = (iz == 2) ? z0 : ((iz == 1) ? z1 : 0.f);
                    p[h][3] = (iz == 2) ? z1 : 0.f;
                    af[0][j] = (short)fb16[(size_t)n * CIN + r16];
                    af[1][j] = (short)fb16[(size_t)n * CIN + 16 + r16];
                }
                #pragma unroll
                for (int nf = 0; nf < 4; ++nf)
                    ((unsigned*)&bP[nf])[jp] = cvtpk(p[0][nf], p[1][nf]);
            }
            #pragma unroll
            for (int nf = 0; nf < 4; ++nf) {
                acc[0][nf] = __builtin_amdgcn_mfma_f32_16x16x32_bf16(
                    af[0], bP[nf], acc[0][nf], 0, 0, 0);
                acc[1][nf] = __builtin_amdgcn_mfma_f32_16x16x32_bf16(
                    af[1], bP[nf], acc[1][nf], 0, 0, 0);
            }
        }
        // write Z row qs as bf16 into swizzled Zl.
        // k = (nf*16+r16)*32 + mf*16 + kgrp*4 + rg
        #pragma unroll
        for (int mf = 0; mf < 2; ++mf)
            #pragma unroll
            for (int nf = 0; nf < 4; ++nf) {
                uint2 dv;
                dv.x = cvtpk(acc[mf][nf][0], acc[mf][nf][1]);
                dv.y = cvtpk(acc[mf][nf][2], acc[mf][nf][3]);
                const int g      = nf * 16 + r16;                 // k>>5
                const int slot   = g * 64 + qs * 4 + mf * 2 + (kgrp >> 1);
                const int stored = slot ^ (g & 7);
                *(uint2*)&Zl[stored * 8 + (kgrp & 1) * 4] = dv;
            }
    }
    __syncthreads();

    // ---------- Phase B: out = Zl x Wfrag (bf16 MFMA) ----------
    {
        const int kw  = w >> 2;      // K-half
        const int nfB = w & 3;       // col-frag
        f32x4 accB = {0.f, 0.f, 0.f, 0.f};
        #pragma unroll 8
        for (int i = 0; i < 32; ++i) {
            const int ks = kw * 32 + i;
            const int stored = (ks * 64 + r16 * 4 + kgrp) ^ (ks & 7);
            const bf16x8 a = *(const bf16x8*)&Zl[stored * 8];
            const bf16x8 b =
                *(const bf16x8*)(Wfrag + (((ks * 4 + nfB) * 64) + lane) * 8);
            accB = __builtin_amdgcn_mfma_f32_16x16x32_bf16(a, b, accB, 0, 0, 0);
        }
        #pragma unroll
        for (int rg = 0; rg < 4; ++rg)
            partial[kw][kgrp * 4 + rg][nfB * 16 + r16] = accB[rg];
    }
    __syncthreads();

    // ---------- Epilogue: reduce K-halves + dense head ----------
    #pragma unroll
    for (int rep = 0; rep < MT16 * COUT / 512; ++rep) {
        const int idx = rep * 512 + t;
        const int r = idx >> 6, o = idx & 63;
        const int q = q0 + r;
        out[q * COUT + o] = partial[0][r][o] + partial[1][r][o];
        float dacc = bd[o];
        #pragma unroll
        for (int i = 0; i < CIN; ++i)
            dacc += feats[q * CIN + i] * Wd[i * COUT + o];
        out[N_PTS * COUT + q * COUT + o] = dacc;
    }
}

// ---------------- Fallback (round-2 monolithic) if ws too small ----------
__global__ __launch_bounds__(256) void conv_dense_kernel(
    const float* __restrict__ feats, const float* __restrict__ pos,
    const float* __restrict__ Wconv, const float* __restrict__ Wd,
    const float* __restrict__ bd,
    const int* __restrict__ en, const float* __restrict__ ev,
    const int* __restrict__ qstart, int strideN,
    float* __restrict__ out)
{
    __shared__ float Z[QB][KF][CIN];
    __shared__ float partial[4][QB][COUT];
    __shared__ int   rec_n[256], rec_b[256];
    __shared__ float rec_fx[256], rec_fy[256], rec_fz[256];
    __shared__ int   qs9[QB + 1];

    const int t = threadIdx.x, wave = t >> 6, lane = t & 63;
    const int q0 = blockIdx.x * QB;
    if (t <= QB) qs9[t] = qstart[q0 + t];
    float* zf = &Z[0][0][0];
    for (int j = t; j < QB * KF * CIN; j += 256) zf[j] = 0.f;
    __syncthreads();
    const int eLo = qs9[0], eHi = qs9[QB];
    const int ci = lane & 31, dbase = lane >> 5;
    for (int cb = eLo; cb < eHi; cb += 256) {
        const int cnt = imin(256, eHi - cb);
        if (t < cnt) {
            const int e = cb + t;
            int q = q0;
            #pragma unroll
            for (int s = 1; s < QB; ++s) if (e >= qs9[s]) q = q0 + s;
            int nn = ((const int*)en)[e];
            int ib; float fx, fy, fz;
            edge_geom(pos, nn, q, ib, fx, fy, fz);
            rec_n[t] = nn; rec_b[t] = ib;
            rec_fx[t] = fx; rec_fy[t] = fy; rec_fz[t] = fz;
        }
        __syncthreads();
        for (int s = 0; s < QB / 4; ++s) {
            const int qs = wave * (QB / 4) + s;
            const int lo = imax(qs9[qs], cb);
            const int hi = imin(qs9[qs + 1], cb + cnt);
            for (int e = lo; e < hi; ++e) {
                const int r = e - cb;
                const int n = rec_n[r], ib = rec_b[r];
                const float fx = rec_fx[r], fy = rec_fy[r], fz = rec_fz[r];
                const float fj = feats[n * CIN + ci];
                const float wxf = dbase ? fx : 1.f - fx;
                #pragma unroll
                for (int dd = 0; dd < 4; ++dd) {
                    const int dy = dd & 1, dz = dd >> 1;
                    const float wv = (dz ? fz : 1.f - fz) * (dy ? fy : 1.f - fy) * wxf;
                    Z[qs][ib + dz * 16 + dy * 4 + dbase][ci] += fj * wv;
                }
            }
        }
        __syncthreads();
    }
    float acc[QB];
    #pragma unroll
    for (int qs = 0; qs < QB; ++qs) acc[qs] = 0.f;
    const int o = lane;
    for (int kk = 0; kk < KF / 4; ++kk) {
        const int kf = wave * (KF / 4) + kk;
        #pragma unroll
        for (int ii = 0; ii < CIN; ii += 4) {
            float4 z4[QB];
            #pragma unroll
            for (int qs = 0; qs < QB; ++qs)
                z4[qs] = *(const float4*)&Z[qs][kf][ii];
            #pragma unroll
            for (int c = 0; c < 4; ++c) {
                const float wv = Wconv[(kf * CIN + ii + c) * COUT + o];
                #pragma unroll
                for (int qs = 0; qs < QB; ++qs)
                    acc[qs] += wv * ((const float*)&z4[qs])[c];
            }
        }
    }
    #pragma unroll
    for (int qs = 0; qs < QB; ++qs) partial[wave][qs][o] = acc[qs];
    __syncthreads();
    for (int s = 0; s < QB / 4; ++s) {
        const int qs = wave * (QB / 4) + s;
        const int q  = q0 + qs;
        out[q * COUT + o] = partial[0][qs][o] + partial[1][qs][o] +
                            partial[2][qs][o] + partial[3][qs][o];
        float dacc = bd[o];
        #pragma unroll
        for (int ii = 0; ii < CIN; ++ii)
            dacc += feats[q * CIN + ii] * Wd[ii * COUT + o];
        out[N_PTS * COUT + q * COUT + o] = dacc;
    }
}

// Repack en to int32 contiguous (fallback path only).
__global__ __launch_bounds__(256) void pack_en_kernel(
    const int* __restrict__ en, int stride, int* __restrict__ en32)
{
    const int e = blockIdx.x * 256 + threadIdx.x;
    if (e < E_PAD) en32[e] = en[e * stride];
}

extern "C" void kernel_launch(void* const* d_in, const int* in_sizes, int n_in,
                              void* d_out, int out_size, void* d_ws, size_t ws_size,
                              hipStream_t stream)
{
    const float* feats = (const float*)d_in[0];
    const float* pos   = (const float*)d_in[1];
    const float* Wconv = (const float*)d_in[2];
    const float* Wd    = (const float*)d_in[3];
    const float* bd    = (const float*)d_in[4];
    const int*   eq    = (const int*)d_in[5];
    const int*   en    = (const int*)d_in[6];
    const float* ev    = (const float*)d_in[7];
    const int strideQ = in_sizes[5] / E_PAD;   // int32 vs int64 hedge
    const int strideN = in_sizes[6] / E_PAD;

    int* qstart = (int*)d_ws;
    const size_t offW  = 81920;                       // Wfrag   (256 KB)
    const size_t offFB = offW + 262144;               // fb16    (1.28 MB)
    const size_t offR  = offFB + (size_t)N_PTS * CIN * 2;  // rec (4 MB)
    const size_t needed = offR + (size_t)E_PAD * 16;

    build_qstart_kernel<<<E_PAD / 256, 256, 0, stream>>>(eq, ev, strideQ, qstart);

    if (ws_size >= needed) {
        unsigned short* Wfrag = (unsigned short*)((char*)d_ws + offW);
        unsigned short* fb16  = (unsigned short*)((char*)d_ws + offFB);
        float4*         rec   = (float4*)((char*)d_ws + offR);
        reorder_w_kernel<<<KDIM * COUT / 256, 256, 0, stream>>>(Wconv, Wfrag);
        feats_bf16_kernel<<<(N_PTS * CIN / 2 + 255) / 256, 256, 0, stream>>>(
            feats, (unsigned*)fb16);
        geom_kernel<<<E_PAD / 256, 256, 0, stream>>>(
            pos, eq, en, strideQ, strideN, rec);
        fused_kernel<<<N_PTS / MT16, 512, 0, stream>>>(
            feats, fb16, rec, Wfrag, Wd, bd, qstart, (float*)d_out);
    } else {
        int* en32 = (int*)((char*)d_ws + offW);
        pack_en_kernel<<<E_PAD / 256, 256, 0, stream>>>(en, strideN, en32);
        conv_dense_kernel<<<N_PTS / QB, 256, 0, stream>>>(
            feats, pos, Wconv, Wd, bd, en32, ev, qstart, 1, (float*)d_out);
    }
}

// Round 10
// 44.255 us; speedup vs baseline: 7.7603x; 1.2102x over previous
//
#include <hip/hip_runtime.h>

#define N_PTS 20000
#define CIN   32
#define COUT  64
#define KK    4
#define KF    64
#define KDIM  2048          // KF*CIN
#define E_PAD 262144
#define EPS   1e-12f
#define FOUR_OVER_PI 1.27323954473516f
#define QB    8             // queries per block (fallback kernel)
#define MT16  16            // queries per block (fused kernel)

// prologue grid partition
#define NB_Q 1024           // build_qstart  (E_PAD/256)
#define NB_G 1024           // geom          (E_PAD/256)
#define NB_W 512            // reorder_w     (131072/256)
#define NB_F 1250           // feats bf16    (320000/256)

typedef __attribute__((ext_vector_type(8))) short bf16x8;
typedef __attribute__((ext_vector_type(4))) float f32x4;

__device__ __forceinline__ float sgnf(float v) {
    return v > 0.f ? 1.f : (v < 0.f ? -1.f : 0.f);
}
__device__ __forceinline__ int imin(int a, int b) { return a < b ? a : b; }
__device__ __forceinline__ int imax(int a, int b) { return a > b ? a : b; }

__device__ __forceinline__ unsigned short f2bf(float f) {   // RNE f32->bf16
    unsigned u = __float_as_uint(f);
    u = u + 0x7fffu + ((u >> 16) & 1u);
    return (unsigned short)(u >> 16);
}

// HW packed conversion: lo16 = bf16(a), hi16 = bf16(b), RNE.
__device__ __forceinline__ unsigned cvtpk(float a, float b) {
    unsigned r;
    asm("v_cvt_pk_bf16_f32 %0, %1, %2" : "=v"(r) : "v"(a), "v"(b));
    return r;
}

// ball_to_cube_volume_preserving + trilinear cell (f32, op-for-op vs ref).
__device__ __forceinline__ void edge_geom(
    const float* __restrict__ pos, int n, int q,
    int& cellb, float& ofx, float& ofy, float& ofz)
{
    const float rx = (pos[n * 3 + 0] - pos[q * 3 + 0]) * 20.f;
    const float ry = (pos[n * 3 + 1] - pos[q * 3 + 1]) * 20.f;
    const float rz = (pos[n * 3 + 2] - pos[q * 3 + 2]) * 20.f;
    const float sq   = rx * rx + ry * ry + rz * rz;
    const float nrm  = sqrtf(fmaxf(sq, EPS));
    const float rxy2 = rx * rx + ry * ry;
    const bool  top  = (1.25f * rz * rz > rxy2);
    const float s_top  = sqrtf(fmaxf(3.f * nrm / (nrm + fabsf(rz) + EPS), EPS));
    const float s_side = nrm / sqrtf(fmaxf(rxy2, EPS));
    float cx = top ? rx * s_top : rx * s_side;
    float cy = top ? ry * s_top : ry * s_side;
    float cz = top ? sgnf(rz) * nrm : 1.5f * rz;
    if (sq < EPS) { cx = 0.f; cy = 0.f; cz = 0.f; }
    const float rc2 = cx * cx + cy * cy;
    const float rxy = sqrtf(fmaxf(rc2, EPS));
    const bool  xbig = fabsf(cy) <= fabsf(cx);
    const float safe_x = (fabsf(cx) > EPS) ? cx : 1.f;
    const float safe_y = (fabsf(cy) > EPS) ? cy : 1.f;
    const float qxv = sgnf(cx) * rxy;
    const float qyv = sgnf(cy) * rxy;
    float bx = xbig ? qxv : qyv * FOUR_OVER_PI * atanf(cx / safe_y);
    float by = xbig ? qxv * FOUR_OVER_PI * atanf(cy / safe_x) : qyv;
    if (rc2 < EPS) { bx = 0.f; by = 0.f; }
    const float ux = fminf(fmaxf((bx + 1.f) * 0.5f * 3.f, 0.f), 3.f);
    const float uy = fminf(fmaxf((by + 1.f) * 0.5f * 3.f, 0.f), 3.f);
    const float uz = fminf(fmaxf((cz + 1.f) * 0.5f * 3.f, 0.f), 3.f);
    const int ix = imin(imax((int)floorf(ux), 0), 2);
    const int iy = imin(imax((int)floorf(uy), 0), 2);
    const int iz = imin(imax((int)floorf(uz), 0), 2);
    cellb = (iz * KK + iy) * KK + ix;
    ofx = ux - (float)ix; ofy = uy - (float)iy; ofz = uz - (float)iz;
}

// One launch, four independent prologue tasks, partitioned by blockIdx.
__global__ __launch_bounds__(256) void prologue_kernel(
    const float* __restrict__ feats, const float* __restrict__ pos,
    const float* __restrict__ Wconv,
    const int* __restrict__ eq, const int* __restrict__ en,
    const float* __restrict__ ev, int strideQ, int strideN,
    int* __restrict__ qstart, unsigned short* __restrict__ Wfrag,
    unsigned* __restrict__ fb, float4* __restrict__ rec)
{
    const int bid = blockIdx.x;
    const int tid = threadIdx.x;
    if (bid < NB_Q) {
        // ---- CSR offsets from sorted edge_q (padding keyed to N_PTS) ----
        const int e = bid * 256 + tid;
        int k = (ev[e] > 0.f) ? eq[e * strideQ] : N_PTS;
        if (k > N_PTS) k = N_PTS;
        int kp = -1;
        if (e > 0) {
            kp = (ev[e - 1] > 0.f) ? eq[(e - 1) * strideQ] : N_PTS;
            if (kp > N_PTS) kp = N_PTS;
        }
        for (int q = kp + 1; q <= k; ++q) qstart[q] = e;
        if (e == E_PAD - 1)
            for (int q = k + 1; q <= N_PTS; ++q) qstart[q] = E_PAD;
    } else if (bid < NB_Q + NB_G) {
        // ---- per-edge geometry record ----
        const int e = (bid - NB_Q) * 256 + tid;
        const int q = eq[e * strideQ];
        const int n = en[e * strideN];
        int ib; float fx, fy, fz;
        edge_geom(pos, n, q, ib, fx, fy, fz);
        float4 r;
        r.x = fx; r.y = fy; r.z = fz;
        r.w = __int_as_float(n | (ib << 16) | (1 << 22));
        rec[e] = r;
    } else if (bid < NB_Q + NB_G + NB_W) {
        // ---- W -> bf16 B-fragment order: Wfrag[ks][nf][lane][j] ----
        const int idx = (bid - NB_Q - NB_G) * 256 + tid;
        const int j    = idx & 7;
        const int lane = (idx >> 3) & 63;
        const int nf   = (idx >> 9) & 3;
        const int ks   = idx >> 11;
        const int k    = ks * 32 + ((lane >> 4) << 3) + j;
        const int col  = nf * 16 + (lane & 15);
        Wfrag[idx] = f2bf(Wconv[k * COUT + col]);
    } else {
        // ---- feats f32 -> bf16 pairs ----
        const int i = (bid - NB_Q - NB_G - NB_W) * 256 + tid;
        if (i < N_PTS * CIN / 2)
            fb[i] = cvtpk(feats[2 * i], feats[2 * i + 1]);
    }
}

// Fused: per-query MFMA scatter (pipelined: ping-pong ebuf, stage chunk
// fi+2 while computing fi; both of the wave's queries flattened into one
// chunk list) + MFMA GEMM vs Wfrag + dense head.
__global__ __launch_bounds__(512, 4) void fused_kernel(
    const float* __restrict__ feats, const unsigned short* __restrict__ fb16,
    const float4* __restrict__ rec,
    const unsigned short* __restrict__ Wfrag,
    const float* __restrict__ Wd, const float* __restrict__ bd,
    const int* __restrict__ qstart, float* __restrict__ out)
{
    __shared__ __align__(16) unsigned short Zl[MT16 * KDIM];   // 64 KB
    __shared__ __align__(16) char scratch[8192];               // 8 KB union
    __shared__ int qs17[MT16 + 1];
    float4 (*ebuf)[2][32]   = (float4 (*)[2][32])scratch;          // phase A
    float  (*partial)[MT16][COUT] = (float (*)[MT16][COUT])scratch; // phase B+

    const int t    = threadIdx.x;
    const int w    = t >> 6;
    const int lane = t & 63;
    const int r16  = lane & 15;
    const int kgrp = lane >> 4;
    const int q0   = blockIdx.x * MT16;

    if (t <= MT16) qs17[t] = qstart[q0 + t];
    __syncthreads();

    // ---------- Phase A: pipelined MFMA scatter ----------
    const int dxc = r16 & 3, dyc = r16 >> 2;   // this lane's cell coords
    {
        const int lo0 = qs17[w * 2],     hi0 = qs17[w * 2 + 1];
        const int lo1 = qs17[w * 2 + 1], hi1 = qs17[w * 2 + 2];
        const int nch0 = imax(1, (hi0 - lo0 + 31) >> 5);
        const int nch1 = imax(1, (hi1 - lo1 + 31) >> 5);
        const int NC   = nch0 + nch1;            // >= 2

        // initial stage: lanes<32 -> flat chunk 0, lanes>=32 -> flat chunk 1
        {
            const int sfi = lane >> 5, l32 = lane & 31;
            const int isq1 = sfi >= nch0;
            const int c    = isq1 ? sfi - nch0 : sfi;
            const int lo   = isq1 ? lo1 : lo0;
            const int hi   = isq1 ? hi1 : hi0;
            const int e    = lo + c * 32 + l32;
            float4 r;
            if (e < hi) r = rec[e];
            else { r.x = 0.f; r.y = 0.f; r.z = 0.f; r.w = __int_as_float(0); }
            ebuf[w][sfi][l32] = r;
        }

        f32x4 acc[2][4];
        #pragma unroll
        for (int mf = 0; mf < 2; ++mf)
            #pragma unroll
            for (int nf = 0; nf < 4; ++nf)
                acc[mf][nf] = (f32x4){0.f, 0.f, 0.f, 0.f};

        for (int fi = 0; fi < NC; ++fi) {
            // query-boundary: flush q0's Z row, restart accumulator
            if (fi == nch0) {
                const int qs = w * 2;
                #pragma unroll
                for (int mf = 0; mf < 2; ++mf)
                    #pragma unroll
                    for (int nf = 0; nf < 4; ++nf) {
                        uint2 dv;
                        dv.x = cvtpk(acc[mf][nf][0], acc[mf][nf][1]);
                        dv.y = cvtpk(acc[mf][nf][2], acc[mf][nf][3]);
                        const int g      = nf * 16 + r16;
                        const int slot   = g * 64 + qs * 4 + mf * 2 + (kgrp >> 1);
                        const int stored = slot ^ (g & 7);
                        *(uint2*)&Zl[stored * 8 + (kgrp & 1) * 4] = dv;
                        acc[mf][nf] = (f32x4){0.f, 0.f, 0.f, 0.f};
                    }
            }
            // compute chunk fi from ebuf[w][fi&1]
            const float4* buf = ebuf[w][fi & 1];
            bf16x8 bP[4], af[2];
            #pragma unroll
            for (int jp = 0; jp < 4; ++jp) {
                float p[2][4];
                #pragma unroll
                for (int h = 0; h < 2; ++h) {
                    const int j = jp * 2 + h;
                    const float4 r = buf[kgrp * 8 + j];
                    const int meta = __float_as_int(r.w);
                    const int n    = meta & 0xFFFF;
                    const int ib   = (meta >> 16) & 63;
                    const float valid = (meta & (1 << 22)) ? 1.f : 0.f;
                    const int ix = ib & 3, iy = (ib >> 2) & 3, iz = ib >> 4;
                    const float wx = (dxc == ix) ? (1.f - r.x)
                                   : ((dxc == ix + 1) ? r.x : 0.f);
                    const float wy = (dyc == iy) ? (1.f - r.y)
                                   : ((dyc == iy + 1) ? r.y : 0.f);
                    const float wxy = wx * wy * valid;
                    const float z0 = wxy * (1.f - r.z), z1 = wxy * r.z;
                    p[h][0] = (iz == 0) ? z0 : 0.f;
                    p[h][1] = (iz == 0) ? z1 : ((iz == 1) ? z0 : 0.f);
                    p[h][2] = (iz == 2) ? z0 : ((iz == 1) ? z1 : 0.f);
                    p[h][3] = (iz == 2) ? z1 : 0.f;
                    af[0][j] = (short)fb16[(size_t)n * CIN + r16];
                    af[1][j] = (short)fb16[(size_t)n * CIN + 16 + r16];
                }
                #pragma unroll
                for (int nf = 0; nf < 4; ++nf)
                    ((unsigned*)&bP[nf])[jp] = cvtpk(p[0][nf], p[1][nf]);
            }
            #pragma unroll
            for (int nf = 0; nf < 4; ++nf) {
                acc[0][nf] = __builtin_amdgcn_mfma_f32_16x16x32_bf16(
                    af[0], bP[nf], acc[0][nf], 0, 0, 0);
                acc[1][nf] = __builtin_amdgcn_mfma_f32_16x16x32_bf16(
                    af[1], bP[nf], acc[1][nf], 0, 0, 0);
            }
            // stage chunk fi+2 into the buffer just consumed (lanes<32)
            const int nfi = fi + 2;
            if (nfi < NC && lane < 32) {
                const int isq1 = nfi >= nch0;
                const int c    = isq1 ? nfi - nch0 : nfi;
                const int lo   = isq1 ? lo1 : lo0;
                const int hi   = isq1 ? hi1 : hi0;
                const int e    = lo + c * 32 + lane;
                float4 r;
                if (e < hi) r = rec[e];
                else { r.x = 0.f; r.y = 0.f; r.z = 0.f;
                       r.w = __int_as_float(0); }
                ebuf[w][fi & 1][lane] = r;
            }
        }
        // flush q1's Z row
        {
            const int qs = w * 2 + 1;
            #pragma unroll
            for (int mf = 0; mf < 2; ++mf)
                #pragma unroll
                for (int nf = 0; nf < 4; ++nf) {
                    uint2 dv;
                    dv.x = cvtpk(acc[mf][nf][0], acc[mf][nf][1]);
                    dv.y = cvtpk(acc[mf][nf][2], acc[mf][nf][3]);
                    const int g      = nf * 16 + r16;
                    const int slot   = g * 64 + qs * 4 + mf * 2 + (kgrp >> 1);
                    const int stored = slot ^ (g & 7);
                    *(uint2*)&Zl[stored * 8 + (kgrp & 1) * 4] = dv;
                }
        }
    }
    __syncthreads();

    // ---------- Phase B: out = Zl x Wfrag (bf16 MFMA) ----------
    {
        const int kw  = w >> 2;      // K-half
        const int nfB = w & 3;       // col-frag
        f32x4 accB = {0.f, 0.f, 0.f, 0.f};
        #pragma unroll 8
        for (int i = 0; i < 32; ++i) {
            const int ks = kw * 32 + i;
            const int stored = (ks * 64 + r16 * 4 + kgrp) ^ (ks & 7);
            const bf16x8 a = *(const bf16x8*)&Zl[stored * 8];
            const bf16x8 b =
                *(const bf16x8*)(Wfrag + (((ks * 4 + nfB) * 64) + lane) * 8);
            accB = __builtin_amdgcn_mfma_f32_16x16x32_bf16(a, b, accB, 0, 0, 0);
        }
        #pragma unroll
        for (int rg = 0; rg < 4; ++rg)
            partial[kw][kgrp * 4 + rg][nfB * 16 + r16] = accB[rg];
    }
    __syncthreads();

    // ---------- Epilogue: reduce K-halves + dense head ----------
    #pragma unroll
    for (int rep = 0; rep < MT16 * COUT / 512; ++rep) {
        const int idx = rep * 512 + t;
        const int r = idx >> 6, o = idx & 63;
        const int q = q0 + r;
        out[q * COUT + o] = partial[0][r][o] + partial[1][r][o];
        float dacc = bd[o];
        #pragma unroll
        for (int i = 0; i < CIN; ++i)
            dacc += feats[q * CIN + i] * Wd[i * COUT + o];
        out[N_PTS * COUT + q * COUT + o] = dacc;
    }
}

// ---------------- Fallback (round-2 monolithic) if ws too small ----------
__global__ __launch_bounds__(256) void conv_dense_kernel(
    const float* __restrict__ feats, const float* __restrict__ pos,
    const float* __restrict__ Wconv, const float* __restrict__ Wd,
    const float* __restrict__ bd,
    const int* __restrict__ en, const float* __restrict__ ev,
    const int* __restrict__ qstart, int strideN,
    float* __restrict__ out)
{
    __shared__ float Z[QB][KF][CIN];
    __shared__ float partial[4][QB][COUT];
    __shared__ int   rec_n[256], rec_b[256];
    __shared__ float rec_fx[256], rec_fy[256], rec_fz[256];
    __shared__ int   qs9[QB + 1];

    const int t = threadIdx.x, wave = t >> 6, lane = t & 63;
    const int q0 = blockIdx.x * QB;
    if (t <= QB) qs9[t] = qstart[q0 + t];
    float* zf = &Z[0][0][0];
    for (int j = t; j < QB * KF * CIN; j += 256) zf[j] = 0.f;
    __syncthreads();
    const int eLo = qs9[0], eHi = qs9[QB];
    const int ci = lane & 31, dbase = lane >> 5;
    for (int cb = eLo; cb < eHi; cb += 256) {
        const int cnt = imin(256, eHi - cb);
        if (t < cnt) {
            const int e = cb + t;
            int q = q0;
            #pragma unroll
            for (int s = 1; s < QB; ++s) if (e >= qs9[s]) q = q0 + s;
            int nn = ((const int*)en)[e];
            int ib; float fx, fy, fz;
            edge_geom(pos, nn, q, ib, fx, fy, fz);
            rec_n[t] = nn; rec_b[t] = ib;
            rec_fx[t] = fx; rec_fy[t] = fy; rec_fz[t] = fz;
        }
        __syncthreads();
        for (int s = 0; s < QB / 4; ++s) {
            const int qs = wave * (QB / 4) + s;
            const int lo = imax(qs9[qs], cb);
            const int hi = imin(qs9[qs + 1], cb + cnt);
            for (int e = lo; e < hi; ++e) {
                const int r = e - cb;
                const int n = rec_n[r], ib = rec_b[r];
                const float fx = rec_fx[r], fy = rec_fy[r], fz = rec_fz[r];
                const float fj = feats[n * CIN + ci];
                const float wxf = dbase ? fx : 1.f - fx;
                #pragma unroll
                for (int dd = 0; dd < 4; ++dd) {
                    const int dy = dd & 1, dz = dd >> 1;
                    const float wv = (dz ? fz : 1.f - fz) * (dy ? fy : 1.f - fy) * wxf;
                    Z[qs][ib + dz * 16 + dy * 4 + dbase][ci] += fj * wv;
                }
            }
        }
        __syncthreads();
    }
    float acc[QB];
    #pragma unroll
    for (int qs = 0; qs < QB; ++qs) acc[qs] = 0.f;
    const int o = lane;
    for (int kk = 0; kk < KF / 4; ++kk) {
        const int kf = wave * (KF / 4) + kk;
        #pragma unroll
        for (int ii = 0; ii < CIN; ii += 4) {
            float4 z4[QB];
            #pragma unroll
            for (int qs = 0; qs < QB; ++qs)
                z4[qs] = *(const float4*)&Z[qs][kf][ii];
            #pragma unroll
            for (int c = 0; c < 4; ++c) {
                const float wv = Wconv[(kf * CIN + ii + c) * COUT + o];
                #pragma unroll
                for (int qs = 0; qs < QB; ++qs)
                    acc[qs] += wv * ((const float*)&z4[qs])[c];
            }
        }
    }
    #pragma unroll
    for (int qs = 0; qs < QB; ++qs) partial[wave][qs][o] = acc[qs];
    __syncthreads();
    for (int s = 0; s < QB / 4; ++s) {
        const int qs = wave * (QB / 4) + s;
        const int q  = q0 + qs;
        out[q * COUT + o] = partial[0][qs][o] + partial[1][qs][o] +
                            partial[2][qs][o] + partial[3][qs][o];
        float dacc = bd[o];
        #pragma unroll
        for (int ii = 0; ii < CIN; ++ii)
            dacc += feats[q * CIN + ii] * Wd[ii * COUT + o];
        out[N_PTS * COUT + q * COUT + o] = dacc;
    }
}

// Repack en to int32 contiguous (fallback path only).
__global__ __launch_bounds__(256) void pack_en_kernel(
    const int* __restrict__ en, int stride, int* __restrict__ en32)
{
    const int e = blockIdx.x * 256 + threadIdx.x;
    if (e < E_PAD) en32[e] = en[e * stride];
}

// qstart-only builder for the fallback path.
__global__ __launch_bounds__(256) void build_qstart_kernel(
    const int* __restrict__ eq, const float* __restrict__ ev,
    int stride, int* __restrict__ qstart)
{
    int e = blockIdx.x * 256 + threadIdx.x;
    if (e >= E_PAD) return;
    int k = (ev[e] > 0.f) ? eq[e * stride] : N_PTS;
    if (k > N_PTS) k = N_PTS;
    int kp = -1;
    if (e > 0) {
        kp = (ev[e - 1] > 0.f) ? eq[(e - 1) * stride] : N_PTS;
        if (kp > N_PTS) kp = N_PTS;
    }
    for (int q = kp + 1; q <= k; ++q) qstart[q] = e;
    if (e == E_PAD - 1) {
        for (int q = k + 1; q <= N_PTS; ++q) qstart[q] = E_PAD;
    }
}

extern "C" void kernel_launch(void* const* d_in, const int* in_sizes, int n_in,
                              void* d_out, int out_size, void* d_ws, size_t ws_size,
                              hipStream_t stream)
{
    const float* feats = (const float*)d_in[0];
    const float* pos   = (const float*)d_in[1];
    const float* Wconv = (const float*)d_in[2];
    const float* Wd    = (const float*)d_in[3];
    const float* bd    = (const float*)d_in[4];
    const int*   eq    = (const int*)d_in[5];
    const int*   en    = (const int*)d_in[6];
    const float* ev    = (const float*)d_in[7];
    const int strideQ = in_sizes[5] / E_PAD;   // int32 vs int64 hedge
    const int strideN = in_sizes[6] / E_PAD;

    int* qstart = (int*)d_ws;
    const size_t offW  = 81920;                       // Wfrag   (256 KB)
    const size_t offFB = offW + 262144;               // fb16    (1.28 MB)
    const size_t offR  = offFB + (size_t)N_PTS * CIN * 2;  // rec (4 MB)
    const size_t needed = offR + (size_t)E_PAD * 16;

    if (ws_size >= needed) {
        unsigned short* Wfrag = (unsigned short*)((char*)d_ws + offW);
        unsigned short* fb16  = (unsigned short*)((char*)d_ws + offFB);
        float4*         rec   = (float4*)((char*)d_ws + offR);
        prologue_kernel<<<NB_Q + NB_G + NB_W + NB_F, 256, 0, stream>>>(
            feats, pos, Wconv, eq, en, ev, strideQ, strideN,
            qstart, Wfrag, (unsigned*)fb16, rec);
        fused_kernel<<<N_PTS / MT16, 512, 0, stream>>>(
            feats, fb16, rec, Wfrag, Wd, bd, qstart, (float*)d_out);
    } else {
        build_qstart_kernel<<<E_PAD / 256, 256, 0, stream>>>(
            eq, ev, strideQ, qstart);
        int* en32 = (int*)((char*)d_ws + offW);
        pack_en_kernel<<<E_PAD / 256, 256, 0, stream>>>(en, strideN, en32);
        conv_dense_kernel<<<N_PTS / QB, 256, 0, stream>>>(
            feats, pos, Wconv, Wd, bd, en32, ev, qstart, 1, (float*)d_out);
    }
}